// Round 8
// baseline (357.192 us; speedup 1.0000x reference)
//
#include <hip/hip_runtime.h>
#include <hip/hip_bf16.h>
#include <math.h>

#define L_SEQ   16384
#define C_DIM   256
#define N_BATCH 4
#define N_HEAD  8
#define D_H     32
#define M_ROWS  (N_BATCH * L_SEQ)   // 65536
#define KV_SPLIT 64
#define SLAB_E  ((size_t)M_ROWS * C_DIM)   // 16,777,216 elems

typedef unsigned short u16;
typedef unsigned int   u32;
typedef short s16x8 __attribute__((ext_vector_type(8)));
typedef float f32x4 __attribute__((ext_vector_type(4)));

// ---- bf16 helpers (bit-exact bf16->f32; RNE f32->bf16) ----------------------
__device__ __forceinline__ float bf2f(u32 lo16) { return __uint_as_float(lo16 << 16); }
__device__ __forceinline__ u16 f2bf(float f) {
    u32 u = __float_as_uint(f);
    u32 rb = ((u >> 16) & 1u) + 0x7fffu;
    return (u16)((u + rb) >> 16);
}

// ---- async global->LDS, 16B per lane ---------------------------------------
__device__ __forceinline__ void gl_lds16(const u16* g, u16* l) {
    __builtin_amdgcn_global_load_lds(
        (__attribute__((address_space(1))) void*)g,
        (__attribute__((address_space(3))) void*)l, 16, 0, 0);
}

// ---------------------------------------------------------------------------
// f32 -> bf16 bulk convert (8 elems/thread/iter)
// ---------------------------------------------------------------------------
__global__ __launch_bounds__(256)
void f32_to_bf16_k(const float* __restrict__ in, u16* __restrict__ out, int n8)
{
    int i = blockIdx.x * blockDim.x + threadIdx.x;
    int stride = gridDim.x * blockDim.x;
    for (; i < n8; i += stride) {
        float4 f0 = ((const float4*)in)[(size_t)i * 2];
        float4 f1 = ((const float4*)in)[(size_t)i * 2 + 1];
        uint4 o;
        o.x = (u32)f2bf(f0.x) | ((u32)f2bf(f0.y) << 16);
        o.y = (u32)f2bf(f0.z) | ((u32)f2bf(f0.w) << 16);
        o.z = (u32)f2bf(f1.x) | ((u32)f2bf(f1.y) << 16);
        o.w = (u32)f2bf(f1.z) | ((u32)f2bf(f1.w) << 16);
        ((uint4*)out)[i] = o;
    }
}

// ---------------------------------------------------------------------------
// All weight transposes in one kernel. W[K][N] f32 -> Wt[rowoff+n][K] bf16.
// ---------------------------------------------------------------------------
__global__ __launch_bounds__(256)
void w_prep(const float* __restrict__ Wq, const float* __restrict__ Wk,
            const float* __restrict__ Wv, const float* __restrict__ Wm,
            const float* __restrict__ W1, const float* __restrict__ W2,
            u16* __restrict__ wqkvt, u16* __restrict__ wmt,
            u16* __restrict__ w1t, u16* __restrict__ w2t)
{
    __shared__ float tile[32][33];
    int bt = blockIdx.x;
    const float* src; u16* dst; int K, N, rowoff, tt;
    if (bt < 192)      { int w = bt >> 6; tt = bt & 63;
                         src = (w == 0) ? Wq : (w == 1) ? Wk : Wv;
                         dst = wqkvt; K = 256; N = 256; rowoff = w * 256; }
    else if (bt < 256) { tt = bt - 192; src = Wm; dst = wmt; K = 256; N = 256; rowoff = 0; }
    else if (bt < 512) { tt = bt - 256; src = W1; dst = w1t; K = 512; N = 512; rowoff = 0; }
    else               { tt = bt - 512; src = W2; dst = w2t; K = 512; N = 256; rowoff = 0; }
    int ntx = N >> 5;
    int n0 = (tt % ntx) * 32, k0 = (tt / ntx) * 32;
    int tx = threadIdx.x & 31, ty = threadIdx.x >> 5;
    #pragma unroll
    for (int i = 0; i < 32; i += 8)
        tile[ty + i][tx] = src[(size_t)(k0 + ty + i) * N + n0 + tx];
    __syncthreads();
    #pragma unroll
    for (int i = 0; i < 32; i += 8)
        dst[(size_t)(rowoff + n0 + ty + i) * K + k0 + tx] = f2bf(tile[tx][ty + i]);
}

// ---------------------------------------------------------------------------
// Persistent bf16 MFMA GEMM. Each block processes tpb output tiles (128x128)
// as ONE flattened (tile x K-step) pipeline: 3-buffer LDS ring (48 KB),
// prefetch depth 2, one s_barrier + one counted vmcnt per step. The ring
// stays full across tile boundaries; epilogue stores overlap next tile's
// staging (post-epilogue wait uses vmcnt(20) to leave stores in flight).
// kc-XOR swizzle both-sides; C^T frags -> 8B stores; XCD-chunked swizzle.
// C = EPI( concat(A1,A2)[M,K] @ Bt^T ), Bt[N][K] bf16.
// EPI: 0=none, 3=relu, 4=qkv split epilogue (q/k/v slabs via col0).
// ---------------------------------------------------------------------------
template<int EPI>
__global__ __launch_bounds__(256)
void gemm_bf16(const u16* __restrict__ A1, const u16* __restrict__ A2,
               int KA, int sA1, int sA2,
               const u16* __restrict__ Bt, int ldb, int bstride,
               u16* __restrict__ C, int ldc, int K, float escale,
               int nx, int tpb)
{
    __shared__ __align__(16) u16 As[3][128 * 32];   // 24 KB
    __shared__ __align__(16) u16 Bs[3][128 * 32];   // 24 KB

    const int tid = threadIdx.x;
    const int nwg = gridDim.x;
    const int cpx = nwg >> 3;
    const int hb  = blockIdx.x;
    const int lb  = (hb & 7) * cpx + (hb >> 3);     // XCD-chunked
    const int w = tid >> 6, lane = tid & 63;
    const int wr = w >> 1, wc = w & 1;
    const int g = lane >> 4, r = lane & 15;
    const int ksteps = K / 32;
    const int lt0 = lb * tpb;
    const int total = tpb * ksteps;

    auto stage = [&](int lt, int kt, int buf) {
        int mt = lt / nx;
        int m0 = mt * 128, n0 = (lt - mt * nx) * 128;
        const u16* Btb = Bt + (size_t)(m0 / L_SEQ) * bstride;
        #pragma unroll
        for (int i = 0; i < 2; ++i) {
            int li  = i * 256 + tid;
            int row = li >> 2, kc = li & 3;
            int kcg = kc ^ ((row >> 1) & 3);        // pre-swizzled source
            int kg = kt * 32 + kcg * 8;
            const u16* Ap = (kg < KA) ? A1 : A2;
            int stride    = (kg < KA) ? sA1 : sA2;
            int col       = (kg < KA) ? kg  : kg - KA;
            gl_lds16(Ap + (size_t)(m0 + row) * stride + col, &As[buf][li * 8]);
            gl_lds16(Btb + (size_t)(n0 + row) * ldb + kt * 32 + kcg * 8,
                     &Bs[buf][li * 8]);
        }
    };

    f32x4 acc[4][4] = {};
    stage(lt0, 0, 0);
    stage(lt0, 1, 1);

    int lt_c = lt0, kt_c = 0, buf_c = 0;
    int lt_s = lt0, kt_s = 2, buf_s = 2;
    int m0c = (lt_c / nx) * 128, n0c = (lt_c - (lt_c / nx) * nx) * 128;
    bool post_epi = false;
    const int gsw = g ^ ((r >> 1) & 3);             // swizzled k-chunk slot

    for (int gs = 0; gs < total; ++gs) {
        // wait for stage(gs) only; newer stages (and epilogue stores) stay
        // in flight across the barrier (FIFO vmcnt semantics).
        if (gs == total - 1)  asm volatile("s_waitcnt vmcnt(0)" ::: "memory");
        else if (post_epi)    asm volatile("s_waitcnt vmcnt(20)" ::: "memory");
        else                  asm volatile("s_waitcnt vmcnt(4)" ::: "memory");
        post_epi = false;
        __builtin_amdgcn_s_barrier();

        if (gs + 2 < total) {
            stage(lt_s, kt_s, buf_s);
            if (++kt_s == ksteps) { kt_s = 0; ++lt_s; }
            if (++buf_s == 3) buf_s = 0;
        }

        s16x8 a[4], b[4];
        #pragma unroll
        for (int mi = 0; mi < 4; ++mi)
            a[mi] = *(const s16x8*)&As[buf_c][(wr * 64 + mi * 16 + r) * 32 + gsw * 8];
        #pragma unroll
        for (int ni = 0; ni < 4; ++ni)
            b[ni] = *(const s16x8*)&Bs[buf_c][(wc * 64 + ni * 16 + r) * 32 + gsw * 8];
        __builtin_amdgcn_s_setprio(1);
        // swapped operands -> C^T frags: reg j = col (ni*16+g*4+j) at row mi*16+r
        #pragma unroll
        for (int mi = 0; mi < 4; ++mi)
            #pragma unroll
            for (int ni = 0; ni < 4; ++ni)
                asm volatile("v_mfma_f32_16x16x32_bf16 %0, %1, %2, %0"
                             : "+v"(acc[mi][ni]) : "v"(b[ni]), "v"(a[mi]));
        __builtin_amdgcn_s_setprio(0);

        if (++kt_c == ksteps) {
            // ---- epilogue for tile (m0c, n0c); overlaps next tile's staging
            asm volatile("s_nop 7");
            asm volatile("s_nop 7");
            #pragma unroll
            for (int mi = 0; mi < 4; ++mi) {
                int row = m0c + wr * 64 + mi * 16 + r;
                #pragma unroll
                for (int ni = 0; ni < 4; ++ni) {
                    int col0 = n0c + wc * 64 + ni * 16 + g * 4;
                    ushort4 o;
                    #pragma unroll
                    for (int j = 0; j < 4; ++j) {
                        float v = acc[mi][ni][j];
                        if (EPI == 3)      v = (v > 0.f) ? v : 0.f;
                        else if (EPI == 4) v = (col0 < 512) ? ((v > 0.f) ? (v + 1.f) : __expf(v))
                                                            : v * escale;
                        (&o.x)[j] = f2bf(v);
                    }
                    if (EPI == 4) {
                        u16* dst = (col0 < 256) ? C + (size_t)row * 256 + col0
                                 : (col0 < 512) ? C + SLAB_E + (size_t)row * 256 + (col0 - 256)
                                                : C + 2 * SLAB_E + (size_t)row * 256 + (col0 - 512);
                        *(ushort4*)dst = o;
                    } else {
                        *(ushort4*)&C[(size_t)row * ldc + col0] = o;
                    }
                    acc[mi][ni] = (f32x4)(0.f);
                }
            }
            kt_c = 0; ++lt_c;
            m0c = (lt_c / nx) * 128;
            n0c = (lt_c - (lt_c / nx) * nx) * 128;
            post_epi = true;
        }
        if (++buf_c == 3) buf_c = 0;
    }
}

// ---------------------------------------------------------------------------
// KV partial over L-chunks: KV[32][32] += K^T v ; Ksum[32] += K. f32 accum.
// ---------------------------------------------------------------------------
__global__ __launch_bounds__(256)
void kv_partial(const u16* __restrict__ Kf, const u16* __restrict__ Vf, int ld,
                float* __restrict__ part)
{
    int b  = blockIdx.x;
    int s  = b & (KV_SPLIT - 1);
    int nh = b / KV_SPLIT;
    int h  = nh & (N_HEAD - 1);
    int n  = nh / N_HEAD;
    int t  = threadIdx.x;

    __shared__ __align__(16) float Ks[32][D_H];
    __shared__ __align__(16) float Vs[32][D_H];

    const int d   = t >> 3;
    const int dv0 = (t & 7) * 4;
    const int lr  = t >> 3;          // 0..31 (staging row)
    const int lc  = (t & 7) * 4;     // staging col (quads)
    const size_t base = ((size_t)n * L_SEQ) * ld + h * D_H;

    float a0 = 0, a1 = 0, a2 = 0, a3 = 0, asum = 0;
    const int CH = L_SEQ / KV_SPLIT;
    for (int l = s * CH; l < s * CH + CH; l += 32) {
        __syncthreads();
        uint2 ku = *(const uint2*)&Kf[base + (size_t)(l + lr) * ld + lc];
        uint2 vu = *(const uint2*)&Vf[base + (size_t)(l + lr) * ld + lc];
        Ks[lr][lc] = bf2f(ku.x & 0xffff); Ks[lr][lc + 1] = bf2f(ku.x >> 16);
        Ks[lr][lc + 2] = bf2f(ku.y & 0xffff); Ks[lr][lc + 3] = bf2f(ku.y >> 16);
        Vs[lr][lc] = bf2f(vu.x & 0xffff); Vs[lr][lc + 1] = bf2f(vu.x >> 16);
        Vs[lr][lc + 2] = bf2f(vu.y & 0xffff); Vs[lr][lc + 3] = bf2f(vu.y >> 16);
        __syncthreads();
        #pragma unroll
        for (int i = 0; i < 32; ++i) {
            float kv = Ks[i][d];
            float4 vv = *(const float4*)&Vs[i][dv0];
            a0 = fmaf(kv, vv.x, a0);
            a1 = fmaf(kv, vv.y, a1);
            a2 = fmaf(kv, vv.z, a2);
            a3 = fmaf(kv, vv.w, a3);
            asum += kv;
        }
    }
    float* p = part + (size_t)b * 1056;
    p[d * D_H + dv0 + 0] = a0;
    p[d * D_H + dv0 + 1] = a1;
    p[d * D_H + dv0 + 2] = a2;
    p[d * D_H + dv0 + 3] = a3;
    if ((t & 7) == 0) p[1024 + d] = asum;
}

__global__ __launch_bounds__(256)
void kv_final(const float* __restrict__ part, float* __restrict__ KV,
              float* __restrict__ Ksum)
{
    int nh = blockIdx.x;
    int t  = threadIdx.x;
    float ax = 0, ay = 0, az = 0, aw = 0, ssum = 0;
    const float* p0 = part + (size_t)nh * KV_SPLIT * 1056;
    for (int s = 0; s < KV_SPLIT; ++s) {
        const float* p = p0 + (size_t)s * 1056;
        float4 v = *(const float4*)&p[t * 4];
        ax += v.x; ay += v.y; az += v.z; aw += v.w;
        if (t < D_H) ssum += p[1024 + t];
    }
    float4 o = make_float4(ax, ay, az, aw);
    *(float4*)&KV[(size_t)nh * 1024 + t * 4] = o;
    if (t < D_H) Ksum[nh * D_H + t] = ssum;
}

// ---------------------------------------------------------------------------
// bdr: BDmat rows in Bt layout for the BDW GEMM.
// bdr[b*256 + n][k] = (n>>5==k>>5) ? KV[b][n>>5][n&31][k&31] : 0
// ---------------------------------------------------------------------------
__global__ __launch_bounds__(256)
void bdr_build(const float* __restrict__ KV, u16* __restrict__ bdr)
{
    int idx = blockIdx.x * 256 + threadIdx.x;      // 0 .. 4*256*256-1
    int b = idx >> 16;
    int n = (idx >> 8) & 255;
    int k = idx & 255;
    float v = ((n >> 5) == (k >> 5))
            ? KV[(((size_t)b * N_HEAD + (n >> 5)) * D_H + (n & 31)) * D_H + (k & 31)]
            : 0.f;
    bdr[idx] = f2bf(v);
}

// ---------------------------------------------------------------------------
// attn_z: q[tok][c] *= L / (q[tok] . Ksum_head(c) + eps), in place.
// ---------------------------------------------------------------------------
#define NT_TOK 32
__global__ __launch_bounds__(256)
void attn_z(u16* __restrict__ q, const float* __restrict__ Ksum)
{
    const int t = threadIdx.x;
    const int w = t >> 6, lane = t & 63;
    const int tok0 = blockIdx.x * NT_TOK;
    const int n = tok0 / L_SEQ;
    float4 ks = *(const float4*)&Ksum[n * C_DIM + lane * 4];

    for (int i = 0; i < NT_TOK; i += 4) {
        int tok = tok0 + i + w;
        u16* qp = q + (size_t)tok * C_DIM + lane * 4;
        uint2 qu = *(const uint2*)qp;
        float q0 = bf2f(qu.x & 0xffff), q1 = bf2f(qu.x >> 16);
        float q2 = bf2f(qu.y & 0xffff), q3 = bf2f(qu.y >> 16);
        float p = q0 * ks.x + q1 * ks.y + q2 * ks.z + q3 * ks.w;
        p += __shfl_xor(p, 1);
        p += __shfl_xor(p, 2);
        p += __shfl_xor(p, 4);
        float z = (float)L_SEQ / (p + 1e-6f);
        uint2 o;
        o.x = (u32)f2bf(q0 * z) | ((u32)f2bf(q1 * z) << 16);
        o.y = (u32)f2bf(q2 * z) | ((u32)f2bf(q3 * z) << 16);
        *(uint2*)qp = o;
    }
}

// ---------------------------------------------------------------------------
// LayerNorm rows of 256, bf16 input. FINAL: out f32 = LN + x residual.
// ---------------------------------------------------------------------------
template<bool FINAL>
__global__ __launch_bounds__(256)
void ln_rows_bf(const u16* __restrict__ X, const float* __restrict__ g,
                const float* __restrict__ b, const float* __restrict__ xres,
                void* __restrict__ Y)
{
    int row  = blockIdx.x * 4 + (threadIdx.x >> 6);
    int lane = threadIdx.x & 63;
    uint2 u = *(const uint2*)(X + (size_t)row * C_DIM + lane * 4);
    float v0 = bf2f(u.x & 0xffff), v1 = bf2f(u.x >> 16);
    float v2 = bf2f(u.y & 0xffff), v3 = bf2f(u.y >> 16);
    float s  = v0 + v1 + v2 + v3;
    float s2 = v0 * v0 + v1 * v1 + v2 * v2 + v3 * v3;
    #pragma unroll
    for (int off = 1; off < 64; off <<= 1) {
        s  += __shfl_xor(s, off);
        s2 += __shfl_xor(s2, off);
    }
    float mu  = s * (1.0f / C_DIM);
    float var = s2 * (1.0f / C_DIM) - mu * mu;
    float rstd = rsqrtf(var + 1e-5f);
    float4 gv = *(const float4*)&g[lane * 4];
    float4 bv = *(const float4*)&b[lane * 4];
    float o0 = (v0 - mu) * rstd * gv.x + bv.x;
    float o1 = (v1 - mu) * rstd * gv.y + bv.y;
    float o2 = (v2 - mu) * rstd * gv.z + bv.z;
    float o3 = (v3 - mu) * rstd * gv.w + bv.w;
    if (FINAL) {
        float4 xv = *(const float4*)&xres[(size_t)row * C_DIM + lane * 4];
        float4 o = make_float4(o0 + xv.x, o1 + xv.y, o2 + xv.z, o3 + xv.w);
        *(float4*)((float*)Y + (size_t)row * C_DIM + lane * 4) = o;
    } else {
        uint2 o;
        o.x = (u32)f2bf(o0) | ((u32)f2bf(o1) << 16);
        o.y = (u32)f2bf(o2) | ((u32)f2bf(o3) << 16);
        *(uint2*)((u16*)Y + (size_t)row * C_DIM + lane * 4) = o;
    }
}

// ---------------------------------------------------------------------------
extern "C" void kernel_launch(void* const* d_in, const int* in_sizes, int n_in,
                              void* d_out, int out_size, void* d_ws, size_t ws_size,
                              hipStream_t stream)
{
    const float* x  = (const float*)d_in[0];
    const float* Wq = (const float*)d_in[1];
    const float* Wk = (const float*)d_in[2];
    const float* Wv = (const float*)d_in[3];
    const float* Wm = (const float*)d_in[4];
    const float* W1 = (const float*)d_in[5];
    const float* W2 = (const float*)d_in[6];
    const float* g1 = (const float*)d_in[7];
    const float* b1 = (const float*)d_in[8];
    const float* g2 = (const float*)d_in[9];
    const float* b2 = (const float*)d_in[10];
    float* out = (float*)d_out;

    u16* xb = (u16*)d_ws;          // slab 0
    u16* q  = xb + SLAB_E;         // slab 1  (becomes q', then h-lo)
    u16* k  = q + SLAB_E;          // slab 2  (dead after kv -> h-hi)
    u16* v  = k + SLAB_E;          // slab 3  (dead after kv -> ln1)
    u16* e  = v + SLAB_E;          // slab 4  (m1, then mlp)
    u16* ln1 = v;
    u16* m1  = e;
    u16* h   = q;                  // spans q..k (M x 512)
    u16* mlp = e;
    // weights (transposed bf16) + small buffers
    u16* wqkvt = e + SLAB_E;               // 768*256
    u16* wmt   = wqkvt + 768 * 256;        // 256*256
    u16* w1t   = wmt + 256 * 256;          // 512*512
    u16* w2t   = w1t + 512 * 512;          // 256*512
    u16* bdr   = w2t + 256 * 512;          // 4*256*256
    u16* bdwt  = bdr + (size_t)N_BATCH * 256 * 256;   // 4*256*256, [c][b*256+k]
    float* KV   = (float*)(bdwt + (size_t)N_BATCH * 256 * 256);
    float* Ksum = KV + (size_t)N_BATCH * N_HEAD * D_H * D_H;
    float* part = Ksum + (size_t)N_BATCH * N_HEAD * D_H;

    dim3 blk(256);
    const float invL = 1.0f / (float)L_SEQ;

    // ---- prep ----
    f32_to_bf16_k<<<2048, blk, 0, stream>>>(x, xb, (int)(SLAB_E / 8));
    w_prep<<<640, blk, 0, stream>>>(Wq, Wk, Wv, Wm, W1, W2, wqkvt, wmt, w1t, w2t);

    // ---- fused QKV projection -> dense q,k,v slabs (3072 tiles, 4/block) ----
    gemm_bf16<4><<<768, blk, 0, stream>>>(
        xb, xb, 256, 256, 256, wqkvt, 256, 0, q, 256, 256, invL, 6, 4);

    // ---- KV reduction ----
    kv_partial<<<N_BATCH * N_HEAD * KV_SPLIT, blk, 0, stream>>>(k, v, 256, part);
    kv_final<<<N_BATCH * N_HEAD, blk, 0, stream>>>(part, KV, Ksum);

    // ---- BDW = BD @ Wm (tiny GEMM), bdwt[c][b*256+k] ----
    bdr_build<<<(N_BATCH * 256 * 256) / 256, blk, 0, stream>>>(KV, bdr);
    gemm_bf16<0><<<16, blk, 0, stream>>>(
        wmt, wmt, 256, 256, 256, bdr, 256, 0, bdwt, 1024, 256, 1.f, 8, 1);

    // ---- q' = q * z  (in place) ----
    attn_z<<<M_ROWS / NT_TOK, blk, 0, stream>>>(q, Ksum);

    // ---- m1 = q' @ BDW_b  (1024 tiles, 4/block) ----
    gemm_bf16<0><<<256, blk, 0, stream>>>(
        q, q, 256, 256, 256, bdwt, 1024, 256, m1, 256, 256, 1.f, 2, 4);
    ln_rows_bf<false><<<M_ROWS / 4, blk, 0, stream>>>(m1, g1, b1, nullptr, (void*)ln1);

    // ---- MLP ----
    gemm_bf16<3><<<512, blk, 0, stream>>>(
        xb, ln1, 256, 256, 256, w1t, 512, 0, h, 512, 512, 1.f, 4, 4);
    gemm_bf16<0><<<256, blk, 0, stream>>>(
        h, h, 512, 512, 512, w2t, 512, 0, mlp, 256, 512, 1.f, 2, 4);

    // ---- LN2 + residual ----
    ln_rows_bf<true><<<M_ROWS / 4, blk, 0, stream>>>(mlp, g2, b2, x, out);
}

// Round 9
// 282.462 us; speedup vs baseline: 1.2646x; 1.2646x over previous
//
#include <hip/hip_runtime.h>
#include <hip/hip_bf16.h>
#include <math.h>

#define L_SEQ   16384
#define C_DIM   256
#define N_BATCH 4
#define N_HEAD  8
#define D_H     32
#define M_ROWS  (N_BATCH * L_SEQ)   // 65536
#define KV_SPLIT 64
#define SLAB_E  ((size_t)M_ROWS * C_DIM)   // 16,777,216 elems

typedef unsigned short u16;
typedef unsigned int   u32;
typedef short s16x8 __attribute__((ext_vector_type(8)));
typedef float f32x4 __attribute__((ext_vector_type(4)));

// ---- bf16 helpers (bit-exact bf16->f32; RNE f32->bf16) ----------------------
__device__ __forceinline__ float bf2f(u32 lo16) { return __uint_as_float(lo16 << 16); }
__device__ __forceinline__ u16 f2bf(float f) {
    u32 u = __float_as_uint(f);
    u32 rb = ((u >> 16) & 1u) + 0x7fffu;
    return (u16)((u + rb) >> 16);
}

// ---- async global->LDS, 16B per lane ---------------------------------------
__device__ __forceinline__ void gl_lds16(const u16* g, u16* l) {
    __builtin_amdgcn_global_load_lds(
        (__attribute__((address_space(1))) void*)g,
        (__attribute__((address_space(3))) void*)l, 16, 0, 0);
}

// ---------------------------------------------------------------------------
// f32 -> bf16 bulk convert (8 elems/thread/iter)
// ---------------------------------------------------------------------------
__global__ __launch_bounds__(256)
void f32_to_bf16_k(const float* __restrict__ in, u16* __restrict__ out, int n8)
{
    int i = blockIdx.x * blockDim.x + threadIdx.x;
    int stride = gridDim.x * blockDim.x;
    for (; i < n8; i += stride) {
        float4 f0 = ((const float4*)in)[(size_t)i * 2];
        float4 f1 = ((const float4*)in)[(size_t)i * 2 + 1];
        uint4 o;
        o.x = (u32)f2bf(f0.x) | ((u32)f2bf(f0.y) << 16);
        o.y = (u32)f2bf(f0.z) | ((u32)f2bf(f0.w) << 16);
        o.z = (u32)f2bf(f1.x) | ((u32)f2bf(f1.y) << 16);
        o.w = (u32)f2bf(f1.z) | ((u32)f2bf(f1.w) << 16);
        ((uint4*)out)[i] = o;
    }
}

// ---------------------------------------------------------------------------
// All weight transposes in one kernel. W[K][N] f32 -> Wt[rowoff+n][K] bf16.
// ---------------------------------------------------------------------------
__global__ __launch_bounds__(256)
void w_prep(const float* __restrict__ Wq, const float* __restrict__ Wk,
            const float* __restrict__ Wv, const float* __restrict__ Wm,
            const float* __restrict__ W1, const float* __restrict__ W2,
            u16* __restrict__ wqkvt, u16* __restrict__ wmt,
            u16* __restrict__ w1t, u16* __restrict__ w2t)
{
    __shared__ float tile[32][33];
    int bt = blockIdx.x;
    const float* src; u16* dst; int K, N, rowoff, tt;
    if (bt < 192)      { int w = bt >> 6; tt = bt & 63;
                         src = (w == 0) ? Wq : (w == 1) ? Wk : Wv;
                         dst = wqkvt; K = 256; N = 256; rowoff = w * 256; }
    else if (bt < 256) { tt = bt - 192; src = Wm; dst = wmt; K = 256; N = 256; rowoff = 0; }
    else if (bt < 512) { tt = bt - 256; src = W1; dst = w1t; K = 512; N = 512; rowoff = 0; }
    else               { tt = bt - 512; src = W2; dst = w2t; K = 512; N = 256; rowoff = 0; }
    int ntx = N >> 5;
    int n0 = (tt % ntx) * 32, k0 = (tt / ntx) * 32;
    int tx = threadIdx.x & 31, ty = threadIdx.x >> 5;
    #pragma unroll
    for (int i = 0; i < 32; i += 8)
        tile[ty + i][tx] = src[(size_t)(k0 + ty + i) * N + n0 + tx];
    __syncthreads();
    #pragma unroll
    for (int i = 0; i < 32; i += 8)
        dst[(size_t)(rowoff + n0 + ty + i) * K + k0 + tx] = f2bf(tile[tx][ty + i]);
}

// ---------------------------------------------------------------------------
// bf16 MFMA GEMM v3. Tile 128x256, BK=32, 4 column-waves (wave = 128 rows x
// 64 cols, acc[8][4], 32 MFMA + 12 ds_read_b128 per wave-step).
// TRUE depth-1 async: 2 LDS buffers + 2 raw s_barriers + counted vmcnt(6):
//   barrier A (readers of buf^1 done) -> stage(kt+1)->buf^1 ->
//   s_waitcnt vmcnt(6) (only stage(kt) drained; kt+1 stays in flight
//   across the MFMAs) -> barrier B -> ds_read+MFMA.
// kc-XOR LDS swizzle both-sides (R6-verified, 0 conflicts). C^T frags.
// XCD-chunked 1D block swizzle (nwg%8==0).
// C = EPI( concat(A1,A2)[M,K] @ Bt^T ), Bt[N][K] bf16.
// EPI: 0=none, 3=relu, 4=qkv split,
//      5=LayerNorm(gw,bw) -> bf16 C            (requires N==256, full rows)
//      6=LayerNorm(gw,bw) + xres -> f32 outf   (requires N==256)
// ---------------------------------------------------------------------------
template<int EPI>
__global__ __launch_bounds__(256)
void gemm_bf16(const u16* __restrict__ A1, const u16* __restrict__ A2,
               int KA, int sA1, int sA2,
               const u16* __restrict__ Bt, int ldb, int bstride,
               u16* __restrict__ C, int ldc, int K, float escale, int nx,
               const float* __restrict__ gw, const float* __restrict__ bw,
               const float* __restrict__ xres, float* __restrict__ outf)
{
    __shared__ __align__(16) u16 As[2][128 * 32];   // 16 KB
    __shared__ __align__(16) u16 Bs[2][256 * 32];   // 32 KB
    __shared__ float red[4][2][128];                // 4 KB (LN reduce)

    const int tid = threadIdx.x;
    const int nwg = gridDim.x;
    const int cpx = nwg >> 3;
    const int hb  = blockIdx.x;
    const int lb  = (hb & 7) * cpx + (hb >> 3);     // XCD-chunked
    const int m0 = (lb / nx) * 128;
    const int n0 = (lb % nx) * 256;
    const int wc = tid >> 6;                        // wave = column quarter
    const int lane = tid & 63;
    const int g = lane >> 4, r = lane & 15;

    const u16* Btb = Bt + (size_t)(m0 / L_SEQ) * bstride;

    f32x4 acc[8][4] = {};

    // 6 gl_lds16 per thread per stage (2 A + 4 B)
    auto stage = [&](int kt, int buf) {
        #pragma unroll
        for (int i = 0; i < 2; ++i) {               // A: 128 rows x 4 kc
            int li  = i * 256 + tid;
            int row = li >> 2, kc = li & 3;
            int kcg = kc ^ ((row >> 1) & 3);        // pre-swizzled source
            int kg = kt * 32 + kcg * 8;
            const u16* Ap = (kg < KA) ? A1 : A2;
            int stride    = (kg < KA) ? sA1 : sA2;
            int col       = (kg < KA) ? kg  : kg - KA;
            gl_lds16(Ap + (size_t)(m0 + row) * stride + col, &As[buf][li * 8]);
        }
        #pragma unroll
        for (int i = 0; i < 4; ++i) {               // B: 256 rows x 4 kc
            int li  = i * 256 + tid;
            int row = li >> 2, kc = li & 3;
            int kcg = kc ^ ((row >> 1) & 3);
            gl_lds16(Btb + (size_t)(n0 + row) * ldb + kt * 32 + kcg * 8,
                     &Bs[buf][li * 8]);
        }
    };

    const int kts = K / 32;
    const int gsw = g ^ ((r >> 1) & 3);             // swizzled k-chunk slot
    stage(0, 0);
    for (int kt = 0; kt < kts; ++kt) {
        const int cur = kt & 1;
        __builtin_amdgcn_s_barrier();               // A: buf^1 readers done
        if (kt + 1 < kts) {
            stage(kt + 1, cur ^ 1);
            asm volatile("s_waitcnt vmcnt(6)" ::: "memory");  // stage(kt) landed
        } else {
            asm volatile("s_waitcnt vmcnt(0)" ::: "memory");
        }
        __builtin_amdgcn_s_barrier();               // B: everyone's stage(kt) done

        s16x8 b[4];
        #pragma unroll
        for (int ni = 0; ni < 4; ++ni)
            b[ni] = *(const s16x8*)&Bs[cur][(wc * 64 + ni * 16 + r) * 32 + gsw * 8];
        __builtin_amdgcn_s_setprio(1);
        #pragma unroll
        for (int mi = 0; mi < 8; ++mi) {
            s16x8 av = *(const s16x8*)&As[cur][(mi * 16 + r) * 32 + gsw * 8];
            // swapped operands -> C^T frag: reg j = col (ni*16+g*4+j), row mi*16+r
            #pragma unroll
            for (int ni = 0; ni < 4; ++ni)
                asm volatile("v_mfma_f32_16x16x32_bf16 %0, %1, %2, %0"
                             : "+v"(acc[mi][ni]) : "v"(b[ni]), "v"(av));
        }
        __builtin_amdgcn_s_setprio(0);
    }

    asm volatile("s_nop 7");
    asm volatile("s_nop 7");
    asm volatile("s_nop 7");

    if (EPI == 5 || EPI == 6) {
        // ---- fused LayerNorm epilogue (N == 256, block owns full rows) ----
        #pragma unroll
        for (int mi = 0; mi < 8; ++mi) {
            float s = 0.f, s2 = 0.f;
            #pragma unroll
            for (int ni = 0; ni < 4; ++ni)
                #pragma unroll
                for (int j = 0; j < 4; ++j) {
                    float v = acc[mi][ni][j];
                    s += v; s2 += v * v;
                }
            s  += __shfl_xor(s, 16);  s  += __shfl_xor(s, 32);
            s2 += __shfl_xor(s2, 16); s2 += __shfl_xor(s2, 32);
            if (g == 0) {
                red[wc][0][mi * 16 + r] = s;
                red[wc][1][mi * 16 + r] = s2;
            }
        }
        __syncthreads();

        float4 gv[4], bv[4];
        #pragma unroll
        for (int ni = 0; ni < 4; ++ni) {
            int c = wc * 64 + ni * 16 + g * 4;
            gv[ni] = *(const float4*)&gw[c];
            bv[ni] = *(const float4*)&bw[c];
        }
        #pragma unroll
        for (int mi = 0; mi < 8; ++mi) {
            int rl = mi * 16 + r;
            float S  = red[0][0][rl] + red[1][0][rl] + red[2][0][rl] + red[3][0][rl];
            float S2 = red[0][1][rl] + red[1][1][rl] + red[2][1][rl] + red[3][1][rl];
            float mu = S * (1.0f / 256.0f);
            float var = S2 * (1.0f / 256.0f) - mu * mu;
            float rstd = rsqrtf(var + 1e-5f);
            size_t row = (size_t)(m0 + rl);
            #pragma unroll
            for (int ni = 0; ni < 4; ++ni) {
                int col0 = wc * 64 + ni * 16 + g * 4;
                float o0 = (acc[mi][ni][0] - mu) * rstd * gv[ni].x + bv[ni].x;
                float o1 = (acc[mi][ni][1] - mu) * rstd * gv[ni].y + bv[ni].y;
                float o2 = (acc[mi][ni][2] - mu) * rstd * gv[ni].z + bv[ni].z;
                float o3 = (acc[mi][ni][3] - mu) * rstd * gv[ni].w + bv[ni].w;
                if (EPI == 6) {
                    float4 xv = *(const float4*)&xres[row * 256 + col0];
                    float4 o = make_float4(o0 + xv.x, o1 + xv.y, o2 + xv.z, o3 + xv.w);
                    *(float4*)&outf[row * 256 + col0] = o;
                } else {
                    ushort4 o;
                    o.x = f2bf(o0); o.y = f2bf(o1); o.z = f2bf(o2); o.w = f2bf(o3);
                    *(ushort4*)&C[row * 256 + col0] = o;
                }
            }
        }
        return;
    }

    #pragma unroll
    for (int mi = 0; mi < 8; ++mi) {
        int row = m0 + mi * 16 + r;
        #pragma unroll
        for (int ni = 0; ni < 4; ++ni) {
            int col0 = n0 + wc * 64 + ni * 16 + g * 4;
            ushort4 o;
            #pragma unroll
            for (int j = 0; j < 4; ++j) {
                float v = acc[mi][ni][j];
                if (EPI == 3)      v = (v > 0.f) ? v : 0.f;
                else if (EPI == 4) v = (col0 < 512) ? ((v > 0.f) ? (v + 1.f) : __expf(v))
                                                    : v * escale;
                (&o.x)[j] = f2bf(v);
            }
            if (EPI == 4) {
                u16* dst = (col0 < 256) ? C + (size_t)row * 256 + col0
                         : (col0 < 512) ? C + SLAB_E + (size_t)row * 256 + (col0 - 256)
                                        : C + 2 * SLAB_E + (size_t)row * 256 + (col0 - 512);
                *(ushort4*)dst = o;
            } else {
                *(ushort4*)&C[(size_t)row * ldc + col0] = o;
            }
        }
    }
}

// ---------------------------------------------------------------------------
// KV partial over L-chunks: KV[32][32] += K^T v ; Ksum[32] += K. f32 accum.
// ---------------------------------------------------------------------------
__global__ __launch_bounds__(256)
void kv_partial(const u16* __restrict__ Kf, const u16* __restrict__ Vf, int ld,
                float* __restrict__ part)
{
    int b  = blockIdx.x;
    int s  = b & (KV_SPLIT - 1);
    int nh = b / KV_SPLIT;
    int h  = nh & (N_HEAD - 1);
    int n  = nh / N_HEAD;
    int t  = threadIdx.x;

    __shared__ __align__(16) float Ks[32][D_H];
    __shared__ __align__(16) float Vs[32][D_H];

    const int d   = t >> 3;
    const int dv0 = (t & 7) * 4;
    const int lr  = t >> 3;          // 0..31 (staging row)
    const int lc  = (t & 7) * 4;     // staging col (quads)
    const size_t base = ((size_t)n * L_SEQ) * ld + h * D_H;

    float a0 = 0, a1 = 0, a2 = 0, a3 = 0, asum = 0;
    const int CH = L_SEQ / KV_SPLIT;
    for (int l = s * CH; l < s * CH + CH; l += 32) {
        __syncthreads();
        uint2 ku = *(const uint2*)&Kf[base + (size_t)(l + lr) * ld + lc];
        uint2 vu = *(const uint2*)&Vf[base + (size_t)(l + lr) * ld + lc];
        Ks[lr][lc] = bf2f(ku.x & 0xffff); Ks[lr][lc + 1] = bf2f(ku.x >> 16);
        Ks[lr][lc + 2] = bf2f(ku.y & 0xffff); Ks[lr][lc + 3] = bf2f(ku.y >> 16);
        Vs[lr][lc] = bf2f(vu.x & 0xffff); Vs[lr][lc + 1] = bf2f(vu.x >> 16);
        Vs[lr][lc + 2] = bf2f(vu.y & 0xffff); Vs[lr][lc + 3] = bf2f(vu.y >> 16);
        __syncthreads();
        #pragma unroll
        for (int i = 0; i < 32; ++i) {
            float kv = Ks[i][d];
            float4 vv = *(const float4*)&Vs[i][dv0];
            a0 = fmaf(kv, vv.x, a0);
            a1 = fmaf(kv, vv.y, a1);
            a2 = fmaf(kv, vv.z, a2);
            a3 = fmaf(kv, vv.w, a3);
            asum += kv;
        }
    }
    float* p = part + (size_t)b * 1056;
    p[d * D_H + dv0 + 0] = a0;
    p[d * D_H + dv0 + 1] = a1;
    p[d * D_H + dv0 + 2] = a2;
    p[d * D_H + dv0 + 3] = a3;
    if ((t & 7) == 0) p[1024 + d] = asum;
}

__global__ __launch_bounds__(256)
void kv_final(const float* __restrict__ part, float* __restrict__ KV,
              float* __restrict__ Ksum)
{
    int nh = blockIdx.x;
    int t  = threadIdx.x;
    float ax = 0, ay = 0, az = 0, aw = 0, ssum = 0;
    const float* p0 = part + (size_t)nh * KV_SPLIT * 1056;
    for (int s = 0; s < KV_SPLIT; ++s) {
        const float* p = p0 + (size_t)s * 1056;
        float4 v = *(const float4*)&p[t * 4];
        ax += v.x; ay += v.y; az += v.z; aw += v.w;
        if (t < D_H) ssum += p[1024 + t];
    }
    float4 o = make_float4(ax, ay, az, aw);
    *(float4*)&KV[(size_t)nh * 1024 + t * 4] = o;
    if (t < D_H) Ksum[nh * D_H + t] = ssum;
}

// ---------------------------------------------------------------------------
// bdr: BDmat rows in Bt layout for the BDW GEMM.
// bdr[b*256 + n][k] = (n>>5==k>>5) ? KV[b][n>>5][n&31][k&31] : 0
// ---------------------------------------------------------------------------
__global__ __launch_bounds__(256)
void bdr_build(const float* __restrict__ KV, u16* __restrict__ bdr)
{
    int idx = blockIdx.x * 256 + threadIdx.x;      // 0 .. 4*256*256-1
    int b = idx >> 16;
    int n = (idx >> 8) & 255;
    int k = idx & 255;
    float v = ((n >> 5) == (k >> 5))
            ? KV[(((size_t)b * N_HEAD + (n >> 5)) * D_H + (n & 31)) * D_H + (k & 31)]
            : 0.f;
    bdr[idx] = f2bf(v);
}

// ---------------------------------------------------------------------------
// attn_z: q[tok][c] *= L / (q[tok] . Ksum_head(c) + eps), in place.
// ---------------------------------------------------------------------------
#define NT_TOK 32
__global__ __launch_bounds__(256)
void attn_z(u16* __restrict__ q, const float* __restrict__ Ksum)
{
    const int t = threadIdx.x;
    const int w = t >> 6, lane = t & 63;
    const int tok0 = blockIdx.x * NT_TOK;
    const int n = tok0 / L_SEQ;
    float4 ks = *(const float4*)&Ksum[n * C_DIM + lane * 4];

    for (int i = 0; i < NT_TOK; i += 4) {
        int tok = tok0 + i + w;
        u16* qp = q + (size_t)tok * C_DIM + lane * 4;
        uint2 qu = *(const uint2*)qp;
        float q0 = bf2f(qu.x & 0xffff), q1 = bf2f(qu.x >> 16);
        float q2 = bf2f(qu.y & 0xffff), q3 = bf2f(qu.y >> 16);
        float p = q0 * ks.x + q1 * ks.y + q2 * ks.z + q3 * ks.w;
        p += __shfl_xor(p, 1);
        p += __shfl_xor(p, 2);
        p += __shfl_xor(p, 4);
        float z = (float)L_SEQ / (p + 1e-6f);
        uint2 o;
        o.x = (u32)f2bf(q0 * z) | ((u32)f2bf(q1 * z) << 16);
        o.y = (u32)f2bf(q2 * z) | ((u32)f2bf(q3 * z) << 16);
        *(uint2*)qp = o;
    }
}

// ---------------------------------------------------------------------------
extern "C" void kernel_launch(void* const* d_in, const int* in_sizes, int n_in,
                              void* d_out, int out_size, void* d_ws, size_t ws_size,
                              hipStream_t stream)
{
    const float* x  = (const float*)d_in[0];
    const float* Wq = (const float*)d_in[1];
    const float* Wk = (const float*)d_in[2];
    const float* Wv = (const float*)d_in[3];
    const float* Wm = (const float*)d_in[4];
    const float* W1 = (const float*)d_in[5];
    const float* W2 = (const float*)d_in[6];
    const float* g1 = (const float*)d_in[7];
    const float* b1 = (const float*)d_in[8];
    const float* g2 = (const float*)d_in[9];
    const float* b2 = (const float*)d_in[10];
    float* out = (float*)d_out;

    u16* xb  = (u16*)d_ws;          // slab 0
    u16* q   = xb + SLAB_E;         // slab 1  (q' after attn_z; h-lo after)
    u16* k   = q + SLAB_E;          // slab 2  (dead after kv -> h-hi)
    u16* v   = k + SLAB_E;          // slab 3  (dead after kv)
    u16* ln1 = v + SLAB_E;          // slab 4
    u16* h   = q;                   // spans q..k (M x 512), q'/k dead by then
    // weights (transposed bf16) + small buffers
    u16* wqkvt = ln1 + SLAB_E;             // 768*256
    u16* wmt   = wqkvt + 768 * 256;        // 256*256
    u16* w1t   = wmt + 256 * 256;          // 512*512
    u16* w2t   = w1t + 512 * 512;          // 256*512
    u16* bdr   = w2t + 256 * 512;          // 4*256*256
    u16* bdwt  = bdr + (size_t)N_BATCH * 256 * 256;   // 4*256*256, [c][b*256+k]
    float* KV   = (float*)(bdwt + (size_t)N_BATCH * 256 * 256);
    float* Ksum = KV + (size_t)N_BATCH * N_HEAD * D_H * D_H;
    float* part = Ksum + (size_t)N_BATCH * N_HEAD * D_H;

    dim3 blk(256);
    const float invL = 1.0f / (float)L_SEQ;

    // ---- prep ----
    f32_to_bf16_k<<<2048, blk, 0, stream>>>(x, xb, (int)(SLAB_E / 8));
    w_prep<<<640, blk, 0, stream>>>(Wq, Wk, Wv, Wm, W1, W2, wqkvt, wmt, w1t, w2t);

    // ---- fused QKV projection -> dense q,k,v slabs (nx=3, BN=256) ----
    gemm_bf16<4><<<(M_ROWS / 128) * 3, blk, 0, stream>>>(
        xb, xb, 256, 256, 256, wqkvt, 256, 0, q, 256, 256, invL, 3,
        nullptr, nullptr, nullptr, nullptr);

    // ---- KV reduction ----
    kv_partial<<<N_BATCH * N_HEAD * KV_SPLIT, blk, 0, stream>>>(k, v, 256, part);
    kv_final<<<N_BATCH * N_HEAD, blk, 0, stream>>>(part, KV, Ksum);

    // ---- BDW = BD @ Wm (tiny GEMM), bdwt[c][b*256+k] ----
    bdr_build<<<(N_BATCH * 256 * 256) / 256, blk, 0, stream>>>(KV, bdr);
    gemm_bf16<0><<<8, blk, 0, stream>>>(
        wmt, wmt, 256, 256, 256, bdr, 256, 0, bdwt, 1024, 256, 1.f, 4,
        nullptr, nullptr, nullptr, nullptr);

    // ---- q' = q * z (in place) ----
    attn_z<<<M_ROWS / NT_TOK, blk, 0, stream>>>(q, Ksum);

    // ---- ln1 = LN(q' @ BDW_b; g1,b1)  (fused epilogue) ----
    gemm_bf16<5><<<M_ROWS / 128, blk, 0, stream>>>(
        q, q, 256, 256, 256, bdwt, 1024, 256, ln1, 256, 256, 1.f, 1,
        g1, b1, nullptr, nullptr);

    // ---- h = relu(concat(xb, ln1) @ W1) ----
    gemm_bf16<3><<<(M_ROWS / 128) * 2, blk, 0, stream>>>(
        xb, ln1, 256, 256, 256, w1t, 512, 0, h, 512, 512, 1.f, 2,
        nullptr, nullptr, nullptr, nullptr);

    // ---- out = x + LN(h @ W2; g2,b2)  (fused epilogue, f32 out) ----
    gemm_bf16<6><<<M_ROWS / 128, blk, 0, stream>>>(
        h, h, 512, 512, 512, w2t, 512, 0, nullptr, 256, 512, 1.f, 1,
        g2, b2, x, out);
}

// Round 10
// 267.725 us; speedup vs baseline: 1.3342x; 1.0550x over previous
//
#include <hip/hip_runtime.h>
#include <hip/hip_bf16.h>
#include <math.h>

#define L_SEQ   16384
#define C_DIM   256
#define N_BATCH 4
#define N_HEAD  8
#define D_H     32
#define M_ROWS  (N_BATCH * L_SEQ)   // 65536
#define KV_SPLIT 64
#define SLAB_E  ((size_t)M_ROWS * C_DIM)   // 16,777,216 elems

typedef unsigned short u16;
typedef unsigned int   u32;
typedef short s16x8 __attribute__((ext_vector_type(8)));
typedef float f32x4 __attribute__((ext_vector_type(4)));

// ---- bf16 helpers (bit-exact bf16->f32; RNE f32->bf16) ----------------------
__device__ __forceinline__ float bf2f(u32 lo16) { return __uint_as_float(lo16 << 16); }
__device__ __forceinline__ u16 f2bf(float f) {
    u32 u = __float_as_uint(f);
    u32 rb = ((u >> 16) & 1u) + 0x7fffu;
    return (u16)((u + rb) >> 16);
}

// ---- async global->LDS, 16B per lane ---------------------------------------
__device__ __forceinline__ void gl_lds16(const u16* g, u16* l) {
    __builtin_amdgcn_global_load_lds(
        (__attribute__((address_space(1))) void*)g,
        (__attribute__((address_space(3))) void*)l, 16, 0, 0);
}

// ---------------------------------------------------------------------------
// f32 -> bf16 bulk convert (8 elems/thread/iter)
// ---------------------------------------------------------------------------
__global__ __launch_bounds__(256)
void f32_to_bf16_k(const float* __restrict__ in, u16* __restrict__ out, int n8)
{
    int i = blockIdx.x * blockDim.x + threadIdx.x;
    int stride = gridDim.x * blockDim.x;
    for (; i < n8; i += stride) {
        float4 f0 = ((const float4*)in)[(size_t)i * 2];
        float4 f1 = ((const float4*)in)[(size_t)i * 2 + 1];
        uint4 o;
        o.x = (u32)f2bf(f0.x) | ((u32)f2bf(f0.y) << 16);
        o.y = (u32)f2bf(f0.z) | ((u32)f2bf(f0.w) << 16);
        o.z = (u32)f2bf(f1.x) | ((u32)f2bf(f1.y) << 16);
        o.w = (u32)f2bf(f1.z) | ((u32)f2bf(f1.w) << 16);
        ((uint4*)out)[i] = o;
    }
}

// ---------------------------------------------------------------------------
// All weight transposes in one kernel. W[K][N] f32 -> Wt[rowoff+n][K] bf16.
// ---------------------------------------------------------------------------
__global__ __launch_bounds__(256)
void w_prep(const float* __restrict__ Wq, const float* __restrict__ Wk,
            const float* __restrict__ Wv, const float* __restrict__ Wm,
            const float* __restrict__ W1, const float* __restrict__ W2,
            u16* __restrict__ wqkvt, u16* __restrict__ wmt,
            u16* __restrict__ w1t, u16* __restrict__ w2t)
{
    __shared__ float tile[32][33];
    int bt = blockIdx.x;
    const float* src; u16* dst; int K, N, rowoff, tt;
    if (bt < 192)      { int w = bt >> 6; tt = bt & 63;
                         src = (w == 0) ? Wq : (w == 1) ? Wk : Wv;
                         dst = wqkvt; K = 256; N = 256; rowoff = w * 256; }
    else if (bt < 256) { tt = bt - 192; src = Wm; dst = wmt; K = 256; N = 256; rowoff = 0; }
    else if (bt < 512) { tt = bt - 256; src = W1; dst = w1t; K = 512; N = 512; rowoff = 0; }
    else               { tt = bt - 512; src = W2; dst = w2t; K = 512; N = 256; rowoff = 0; }
    int ntx = N >> 5;
    int n0 = (tt % ntx) * 32, k0 = (tt / ntx) * 32;
    int tx = threadIdx.x & 31, ty = threadIdx.x >> 5;
    #pragma unroll
    for (int i = 0; i < 32; i += 8)
        tile[ty + i][tx] = src[(size_t)(k0 + ty + i) * N + n0 + tx];
    __syncthreads();
    #pragma unroll
    for (int i = 0; i < 32; i += 8)
        dst[(size_t)(rowoff + n0 + ty + i) * K + k0 + tx] = f2bf(tile[tx][ty + i]);
}

// ---------------------------------------------------------------------------
// gemm128: bf16 MFMA GEMM, tile 128x128, BK=32, 4 waves (2x2), wave tile
// 64x64 (acc[4][4] = 64 VGPR -> ~4 blocks/CU with 32 KB LDS).
// TRUE depth-1 async: 2 LDS buffers + 2 raw s_barriers + counted vmcnt(4):
//   barrier A (readers of buf^1 done) -> stage(kt+1)->buf^1 ->
//   vmcnt(4) (stage kt landed; kt+1 in flight across MFMAs) -> barrier B.
// kc-XOR swizzle both-sides (0 conflicts, R6-verified). C^T frags -> 8B
// stores. XCD-chunked 1D swizzle (nwg%8==0).
// EPI: 0=none, 3=relu, 4=qkv split (q/k/v slabs via col0, ldc fixed 256).
// ---------------------------------------------------------------------------
template<int EPI>
__global__ __launch_bounds__(256)
void gemm128(const u16* __restrict__ A1, const u16* __restrict__ A2,
             int KA, int sA1, int sA2,
             const u16* __restrict__ Bt, int ldb, int bstride,
             u16* __restrict__ C, int ldc, int K, float escale, int nx)
{
    __shared__ __align__(16) u16 As[2][128 * 32];   // 16 KB
    __shared__ __align__(16) u16 Bs[2][128 * 32];   // 16 KB

    const int tid = threadIdx.x;
    const int nwg = gridDim.x;
    const int cpx = nwg >> 3;
    const int hb  = blockIdx.x;
    const int lb  = (hb & 7) * cpx + (hb >> 3);     // XCD-chunked
    const int m0 = (lb / nx) * 128;
    const int n0 = (lb % nx) * 128;
    const int w = tid >> 6, lane = tid & 63;
    const int wr = w >> 1, wc = w & 1;
    const int g = lane >> 4, r = lane & 15;

    Bt += (size_t)(m0 / L_SEQ) * bstride;

    f32x4 acc[4][4] = {};

    // 4 gl_lds16 per thread per stage (2 A + 2 B)
    auto stage = [&](int kt, int buf) {
        #pragma unroll
        for (int i = 0; i < 2; ++i) {
            int li  = i * 256 + tid;
            int row = li >> 2, kc = li & 3;
            int kcg = kc ^ ((row >> 1) & 3);        // pre-swizzled source
            int kg = kt * 32 + kcg * 8;
            const u16* Ap = (kg < KA) ? A1 : A2;
            int stride    = (kg < KA) ? sA1 : sA2;
            int col       = (kg < KA) ? kg  : kg - KA;
            gl_lds16(Ap + (size_t)(m0 + row) * stride + col, &As[buf][li * 8]);
            gl_lds16(Bt + (size_t)(n0 + row) * ldb + kt * 32 + kcg * 8,
                     &Bs[buf][li * 8]);
        }
    };

    const int kts = K / 32;
    const int gsw = g ^ ((r >> 1) & 3);             // swizzled k-chunk slot
    stage(0, 0);
    for (int kt = 0; kt < kts; ++kt) {
        const int cur = kt & 1;
        asm volatile("s_barrier" ::: "memory");     // A: buf^1 readers done
        if (kt + 1 < kts) {
            stage(kt + 1, cur ^ 1);
            asm volatile("s_waitcnt vmcnt(4)" ::: "memory");  // stage(kt) landed
        } else {
            asm volatile("s_waitcnt vmcnt(0)" ::: "memory");
        }
        asm volatile("s_barrier" ::: "memory");     // B: all waves' stage(kt) done

        s16x8 a[4], b[4];
        #pragma unroll
        for (int mi = 0; mi < 4; ++mi)
            a[mi] = *(const s16x8*)&As[cur][(wr * 64 + mi * 16 + r) * 32 + gsw * 8];
        #pragma unroll
        for (int ni = 0; ni < 4; ++ni)
            b[ni] = *(const s16x8*)&Bs[cur][(wc * 64 + ni * 16 + r) * 32 + gsw * 8];
        __builtin_amdgcn_s_setprio(1);
        // swapped operands -> C^T frags: reg j = col (ni*16+g*4+j), row mi*16+r
        #pragma unroll
        for (int mi = 0; mi < 4; ++mi)
            #pragma unroll
            for (int ni = 0; ni < 4; ++ni)
                asm volatile("v_mfma_f32_16x16x32_bf16 %0, %1, %2, %0"
                             : "+v"(acc[mi][ni]) : "v"(b[ni]), "v"(a[mi]));
        __builtin_amdgcn_s_setprio(0);
    }

    asm volatile("s_nop 7");
    asm volatile("s_nop 7");
    asm volatile("s_nop 7");

    #pragma unroll
    for (int mi = 0; mi < 4; ++mi) {
        int row = m0 + wr * 64 + mi * 16 + r;
        #pragma unroll
        for (int ni = 0; ni < 4; ++ni) {
            int col0 = n0 + wc * 64 + ni * 16 + g * 4;
            ushort4 o;
            #pragma unroll
            for (int j = 0; j < 4; ++j) {
                float v = acc[mi][ni][j];
                if (EPI == 3)      v = (v > 0.f) ? v : 0.f;
                else if (EPI == 4) v = (col0 < 512) ? ((v > 0.f) ? (v + 1.f) : __expf(v))
                                                    : v * escale;
                (&o.x)[j] = f2bf(v);
            }
            if (EPI == 4) {
                u16* dst = (col0 < 256) ? C + (size_t)row * 256 + col0
                         : (col0 < 512) ? C + SLAB_E + (size_t)row * 256 + (col0 - 256)
                                        : C + 2 * SLAB_E + (size_t)row * 256 + (col0 - 512);
                *(ushort4*)dst = o;
            } else {
                *(ushort4*)&C[(size_t)row * ldc + col0] = o;
            }
        }
    }
}

// ---------------------------------------------------------------------------
// gemm_ln: 128x256-tile GEMM with fused LayerNorm epilogue (R9-proven).
// EPI: 5=LN(gw,bw)->bf16 C; 6=LN(gw,bw)+xres->f32 outf. N==256 (full rows).
// ---------------------------------------------------------------------------
template<int EPI>
__global__ __launch_bounds__(256)
void gemm_ln(const u16* __restrict__ A1, const u16* __restrict__ A2,
             int KA, int sA1, int sA2,
             const u16* __restrict__ Bt, int ldb, int bstride,
             u16* __restrict__ C, int ldc, int K, float escale, int nx,
             const float* __restrict__ gw, const float* __restrict__ bw,
             const float* __restrict__ xres, float* __restrict__ outf)
{
    __shared__ __align__(16) u16 As[2][128 * 32];   // 16 KB
    __shared__ __align__(16) u16 Bs[2][256 * 32];   // 32 KB
    __shared__ float red[4][2][128];                // 4 KB (LN reduce)

    const int tid = threadIdx.x;
    const int nwg = gridDim.x;
    const int cpx = nwg >> 3;
    const int hb  = blockIdx.x;
    const int lb  = (hb & 7) * cpx + (hb >> 3);     // XCD-chunked
    const int m0 = (lb / nx) * 128;
    const int n0 = (lb % nx) * 256;
    const int wc = tid >> 6;                        // wave = column quarter
    const int lane = tid & 63;
    const int g = lane >> 4, r = lane & 15;

    const u16* Btb = Bt + (size_t)(m0 / L_SEQ) * bstride;

    f32x4 acc[8][4] = {};

    auto stage = [&](int kt, int buf) {
        #pragma unroll
        for (int i = 0; i < 2; ++i) {               // A: 128 rows x 4 kc
            int li  = i * 256 + tid;
            int row = li >> 2, kc = li & 3;
            int kcg = kc ^ ((row >> 1) & 3);
            int kg = kt * 32 + kcg * 8;
            const u16* Ap = (kg < KA) ? A1 : A2;
            int stride    = (kg < KA) ? sA1 : sA2;
            int col       = (kg < KA) ? kg  : kg - KA;
            gl_lds16(Ap + (size_t)(m0 + row) * stride + col, &As[buf][li * 8]);
        }
        #pragma unroll
        for (int i = 0; i < 4; ++i) {               // B: 256 rows x 4 kc
            int li  = i * 256 + tid;
            int row = li >> 2, kc = li & 3;
            int kcg = kc ^ ((row >> 1) & 3);
            gl_lds16(Btb + (size_t)(n0 + row) * ldb + kt * 32 + kcg * 8,
                     &Bs[buf][li * 8]);
        }
    };

    const int kts = K / 32;
    const int gsw = g ^ ((r >> 1) & 3);
    stage(0, 0);
    for (int kt = 0; kt < kts; ++kt) {
        const int cur = kt & 1;
        asm volatile("s_barrier" ::: "memory");
        if (kt + 1 < kts) {
            stage(kt + 1, cur ^ 1);
            asm volatile("s_waitcnt vmcnt(6)" ::: "memory");
        } else {
            asm volatile("s_waitcnt vmcnt(0)" ::: "memory");
        }
        asm volatile("s_barrier" ::: "memory");

        s16x8 b[4];
        #pragma unroll
        for (int ni = 0; ni < 4; ++ni)
            b[ni] = *(const s16x8*)&Bs[cur][(wc * 64 + ni * 16 + r) * 32 + gsw * 8];
        __builtin_amdgcn_s_setprio(1);
        #pragma unroll
        for (int mi = 0; mi < 8; ++mi) {
            s16x8 av = *(const s16x8*)&As[cur][(mi * 16 + r) * 32 + gsw * 8];
            #pragma unroll
            for (int ni = 0; ni < 4; ++ni)
                asm volatile("v_mfma_f32_16x16x32_bf16 %0, %1, %2, %0"
                             : "+v"(acc[mi][ni]) : "v"(b[ni]), "v"(av));
        }
        __builtin_amdgcn_s_setprio(0);
    }

    asm volatile("s_nop 7");
    asm volatile("s_nop 7");
    asm volatile("s_nop 7");

    // ---- fused LayerNorm epilogue (N == 256, block owns full rows) ----
    #pragma unroll
    for (int mi = 0; mi < 8; ++mi) {
        float s = 0.f, s2 = 0.f;
        #pragma unroll
        for (int ni = 0; ni < 4; ++ni)
            #pragma unroll
            for (int j = 0; j < 4; ++j) {
                float v = acc[mi][ni][j];
                s += v; s2 += v * v;
            }
        s  += __shfl_xor(s, 16);  s  += __shfl_xor(s, 32);
        s2 += __shfl_xor(s2, 16); s2 += __shfl_xor(s2, 32);
        if (g == 0) {
            red[wc][0][mi * 16 + r] = s;
            red[wc][1][mi * 16 + r] = s2;
        }
    }
    __syncthreads();

    float4 gv[4], bv[4];
    #pragma unroll
    for (int ni = 0; ni < 4; ++ni) {
        int c = wc * 64 + ni * 16 + g * 4;
        gv[ni] = *(const float4*)&gw[c];
        bv[ni] = *(const float4*)&bw[c];
    }
    #pragma unroll
    for (int mi = 0; mi < 8; ++mi) {
        int rl = mi * 16 + r;
        float S  = red[0][0][rl] + red[1][0][rl] + red[2][0][rl] + red[3][0][rl];
        float S2 = red[0][1][rl] + red[1][1][rl] + red[2][1][rl] + red[3][1][rl];
        float mu = S * (1.0f / 256.0f);
        float var = S2 * (1.0f / 256.0f) - mu * mu;
        float rstd = rsqrtf(var + 1e-5f);
        size_t row = (size_t)(m0 + rl);
        #pragma unroll
        for (int ni = 0; ni < 4; ++ni) {
            int col0 = wc * 64 + ni * 16 + g * 4;
            float o0 = (acc[mi][ni][0] - mu) * rstd * gv[ni].x + bv[ni].x;
            float o1 = (acc[mi][ni][1] - mu) * rstd * gv[ni].y + bv[ni].y;
            float o2 = (acc[mi][ni][2] - mu) * rstd * gv[ni].z + bv[ni].z;
            float o3 = (acc[mi][ni][3] - mu) * rstd * gv[ni].w + bv[ni].w;
            if (EPI == 6) {
                float4 xv = *(const float4*)&xres[row * 256 + col0];
                float4 o = make_float4(o0 + xv.x, o1 + xv.y, o2 + xv.z, o3 + xv.w);
                *(float4*)&outf[row * 256 + col0] = o;
            } else {
                ushort4 o;
                o.x = f2bf(o0); o.y = f2bf(o1); o.z = f2bf(o2); o.w = f2bf(o3);
                *(ushort4*)&C[row * 256 + col0] = o;
            }
        }
    }
}

// ---------------------------------------------------------------------------
// KV partial over L-chunks: KV[32][32] += K^T v ; Ksum[32] += K. f32 accum.
// ---------------------------------------------------------------------------
__global__ __launch_bounds__(256)
void kv_partial(const u16* __restrict__ Kf, const u16* __restrict__ Vf, int ld,
                float* __restrict__ part)
{
    int b  = blockIdx.x;
    int s  = b & (KV_SPLIT - 1);
    int nh = b / KV_SPLIT;
    int h  = nh & (N_HEAD - 1);
    int n  = nh / N_HEAD;
    int t  = threadIdx.x;

    __shared__ __align__(16) float Ks[32][D_H];
    __shared__ __align__(16) float Vs[32][D_H];

    const int d   = t >> 3;
    const int dv0 = (t & 7) * 4;
    const int lr  = t >> 3;
    const int lc  = (t & 7) * 4;
    const size_t base = ((size_t)n * L_SEQ) * ld + h * D_H;

    float a0 = 0, a1 = 0, a2 = 0, a3 = 0, asum = 0;
    const int CH = L_SEQ / KV_SPLIT;
    for (int l = s * CH; l < s * CH + CH; l += 32) {
        __syncthreads();
        uint2 ku = *(const uint2*)&Kf[base + (size_t)(l + lr) * ld + lc];
        uint2 vu = *(const uint2*)&Vf[base + (size_t)(l + lr) * ld + lc];
        Ks[lr][lc] = bf2f(ku.x & 0xffff); Ks[lr][lc + 1] = bf2f(ku.x >> 16);
        Ks[lr][lc + 2] = bf2f(ku.y & 0xffff); Ks[lr][lc + 3] = bf2f(ku.y >> 16);
        Vs[lr][lc] = bf2f(vu.x & 0xffff); Vs[lr][lc + 1] = bf2f(vu.x >> 16);
        Vs[lr][lc + 2] = bf2f(vu.y & 0xffff); Vs[lr][lc + 3] = bf2f(vu.y >> 16);
        __syncthreads();
        #pragma unroll
        for (int i = 0; i < 32; ++i) {
            float kv = Ks[i][d];
            float4 vv = *(const float4*)&Vs[i][dv0];
            a0 = fmaf(kv, vv.x, a0);
            a1 = fmaf(kv, vv.y, a1);
            a2 = fmaf(kv, vv.z, a2);
            a3 = fmaf(kv, vv.w, a3);
            asum += kv;
        }
    }
    float* p = part + (size_t)b * 1056;
    p[d * D_H + dv0 + 0] = a0;
    p[d * D_H + dv0 + 1] = a1;
    p[d * D_H + dv0 + 2] = a2;
    p[d * D_H + dv0 + 3] = a3;
    if ((t & 7) == 0) p[1024 + d] = asum;
}

__global__ __launch_bounds__(256)
void kv_final(const float* __restrict__ part, float* __restrict__ KV,
              float* __restrict__ Ksum)
{
    int nh = blockIdx.x;
    int t  = threadIdx.x;
    float ax = 0, ay = 0, az = 0, aw = 0, ssum = 0;
    const float* p0 = part + (size_t)nh * KV_SPLIT * 1056;
    for (int s = 0; s < KV_SPLIT; ++s) {
        const float* p = p0 + (size_t)s * 1056;
        float4 v = *(const float4*)&p[t * 4];
        ax += v.x; ay += v.y; az += v.z; aw += v.w;
        if (t < D_H) ssum += p[1024 + t];
    }
    float4 o = make_float4(ax, ay, az, aw);
    *(float4*)&KV[(size_t)nh * 1024 + t * 4] = o;
    if (t < D_H) Ksum[nh * D_H + t] = ssum;
}

// ---------------------------------------------------------------------------
// bdr: BDmat rows in Bt layout for the BDW GEMM.
// bdr[b*256 + n][k] = (n>>5==k>>5) ? KV[b][n>>5][n&31][k&31] : 0
// ---------------------------------------------------------------------------
__global__ __launch_bounds__(256)
void bdr_build(const float* __restrict__ KV, u16* __restrict__ bdr)
{
    int idx = blockIdx.x * 256 + threadIdx.x;      // 0 .. 4*256*256-1
    int b = idx >> 16;
    int n = (idx >> 8) & 255;
    int k = idx & 255;
    float v = ((n >> 5) == (k >> 5))
            ? KV[(((size_t)b * N_HEAD + (n >> 5)) * D_H + (n & 31)) * D_H + (k & 31)]
            : 0.f;
    bdr[idx] = f2bf(v);
}

// ---------------------------------------------------------------------------
// attn_z: q[tok][c] *= L / (q[tok] . Ksum_head(c) + eps), in place.
// ---------------------------------------------------------------------------
#define NT_TOK 32
__global__ __launch_bounds__(256)
void attn_z(u16* __restrict__ q, const float* __restrict__ Ksum)
{
    const int t = threadIdx.x;
    const int w = t >> 6, lane = t & 63;
    const int tok0 = blockIdx.x * NT_TOK;
    const int n = tok0 / L_SEQ;
    float4 ks = *(const float4*)&Ksum[n * C_DIM + lane * 4];

    for (int i = 0; i < NT_TOK; i += 4) {
        int tok = tok0 + i + w;
        u16* qp = q + (size_t)tok * C_DIM + lane * 4;
        uint2 qu = *(const uint2*)qp;
        float q0 = bf2f(qu.x & 0xffff), q1 = bf2f(qu.x >> 16);
        float q2 = bf2f(qu.y & 0xffff), q3 = bf2f(qu.y >> 16);
        float p = q0 * ks.x + q1 * ks.y + q2 * ks.z + q3 * ks.w;
        p += __shfl_xor(p, 1);
        p += __shfl_xor(p, 2);
        p += __shfl_xor(p, 4);
        float z = (float)L_SEQ / (p + 1e-6f);
        uint2 o;
        o.x = (u32)f2bf(q0 * z) | ((u32)f2bf(q1 * z) << 16);
        o.y = (u32)f2bf(q2 * z) | ((u32)f2bf(q3 * z) << 16);
        *(uint2*)qp = o;
    }
}

// ---------------------------------------------------------------------------
extern "C" void kernel_launch(void* const* d_in, const int* in_sizes, int n_in,
                              void* d_out, int out_size, void* d_ws, size_t ws_size,
                              hipStream_t stream)
{
    const float* x  = (const float*)d_in[0];
    const float* Wq = (const float*)d_in[1];
    const float* Wk = (const float*)d_in[2];
    const float* Wv = (const float*)d_in[3];
    const float* Wm = (const float*)d_in[4];
    const float* W1 = (const float*)d_in[5];
    const float* W2 = (const float*)d_in[6];
    const float* g1 = (const float*)d_in[7];
    const float* b1 = (const float*)d_in[8];
    const float* g2 = (const float*)d_in[9];
    const float* b2 = (const float*)d_in[10];
    float* out = (float*)d_out;

    u16* xb  = (u16*)d_ws;          // slab 0
    u16* q   = xb + SLAB_E;         // slab 1  (q' after attn_z; h-lo after)
    u16* k   = q + SLAB_E;          // slab 2  (dead after kv -> h-hi)
    u16* v   = k + SLAB_E;          // slab 3  (dead after kv)
    u16* ln1 = v + SLAB_E;          // slab 4
    u16* h   = q;                   // spans q..k (M x 512), q'/k dead by then
    // weights (transposed bf16) + small buffers
    u16* wqkvt = ln1 + SLAB_E;             // 768*256
    u16* wmt   = wqkvt + 768 * 256;        // 256*256
    u16* w1t   = wmt + 256 * 256;          // 512*512
    u16* w2t   = w1t + 512 * 512;          // 256*512
    u16* bdr   = w2t + 256 * 512;          // 4*256*256
    u16* bdwt  = bdr + (size_t)N_BATCH * 256 * 256;   // 4*256*256, [c][b*256+k]
    float* KV   = (float*)(bdwt + (size_t)N_BATCH * 256 * 256);
    float* Ksum = KV + (size_t)N_BATCH * N_HEAD * D_H * D_H;
    float* part = Ksum + (size_t)N_BATCH * N_HEAD * D_H;

    dim3 blk(256);
    const float invL = 1.0f / (float)L_SEQ;

    // ---- prep ----
    f32_to_bf16_k<<<2048, blk, 0, stream>>>(x, xb, (int)(SLAB_E / 8));
    w_prep<<<640, blk, 0, stream>>>(Wq, Wk, Wv, Wm, W1, W2, wqkvt, wmt, w1t, w2t);

    // ---- fused QKV projection -> dense q,k,v slabs (128x128 tiles, nx=6) ----
    gemm128<4><<<(M_ROWS / 128) * 6, blk, 0, stream>>>(
        xb, xb, 256, 256, 256, wqkvt, 256, 0, q, 256, 256, invL, 6);

    // ---- KV reduction ----
    kv_partial<<<N_BATCH * N_HEAD * KV_SPLIT, blk, 0, stream>>>(k, v, 256, part);
    kv_final<<<N_BATCH * N_HEAD, blk, 0, stream>>>(part, KV, Ksum);

    // ---- BDW = BD @ Wm (tiny GEMM), bdwt[c][b*256+k] ----
    bdr_build<<<(N_BATCH * 256 * 256) / 256, blk, 0, stream>>>(KV, bdr);
    gemm128<0><<<16, blk, 0, stream>>>(
        wmt, wmt, 256, 256, 256, bdr, 256, 0, bdwt, 1024, 256, 1.f, 8);

    // ---- q' = q * z (in place) ----
    attn_z<<<M_ROWS / NT_TOK, blk, 0, stream>>>(q, Ksum);

    // ---- ln1 = LN(q' @ BDW_b; g1,b1)  (fused epilogue) ----
    gemm_ln<5><<<M_ROWS / 128, blk, 0, stream>>>(
        q, q, 256, 256, 256, bdwt, 1024, 256, ln1, 256, 256, 1.f, 1,
        g1, b1, nullptr, nullptr);

    // ---- h = relu(concat(xb, ln1) @ W1)  (128x128 tiles, nx=4) ----
    gemm128<3><<<(M_ROWS / 128) * 4, blk, 0, stream>>>(
        xb, ln1, 256, 256, 256, w1t, 512, 0, h, 512, 512, 1.f, 4);

    // ---- out = x + LN(h @ W2; g2,b2)  (fused epilogue, f32 out) ----
    gemm_ln<6><<<M_ROWS / 128, blk, 0, stream>>>(
        h, h, 512, 512, 512, w2t, 512, 0, nullptr, 256, 512, 1.f, 1,
        g2, b2, x, out);
}

// Round 11
// 237.636 us; speedup vs baseline: 1.5031x; 1.1266x over previous
//
#include <hip/hip_runtime.h>
#include <hip/hip_bf16.h>
#include <math.h>

#define L_SEQ   16384
#define C_DIM   256
#define N_BATCH 4
#define N_HEAD  8
#define D_H     32
#define M_ROWS  (N_BATCH * L_SEQ)   // 65536
#define KV_SPLIT 64
#define SLAB_E  ((size_t)M_ROWS * C_DIM)   // 16,777,216 elems

typedef unsigned short u16;
typedef unsigned int   u32;
typedef short s16x8 __attribute__((ext_vector_type(8)));
typedef float f32x4 __attribute__((ext_vector_type(4)));

// ---- bf16 helpers (bit-exact bf16->f32; RNE f32->bf16) ----------------------
__device__ __forceinline__ float bf2f(u32 lo16) { return __uint_as_float(lo16 << 16); }
__device__ __forceinline__ u16 f2bf(float f) {
    u32 u = __float_as_uint(f);
    u32 rb = ((u >> 16) & 1u) + 0x7fffu;
    return (u16)((u + rb) >> 16);
}

// ---- async global->LDS, 16B per lane ---------------------------------------
__device__ __forceinline__ void gl_lds16(const u16* g, u16* l) {
    __builtin_amdgcn_global_load_lds(
        (__attribute__((address_space(1))) void*)g,
        (__attribute__((address_space(3))) void*)l, 16, 0, 0);
}

// ---------------------------------------------------------------------------
// f32 -> bf16 bulk convert (8 elems/thread/iter)
// ---------------------------------------------------------------------------
__global__ __launch_bounds__(256)
void f32_to_bf16_k(const float* __restrict__ in, u16* __restrict__ out, int n8)
{
    int i = blockIdx.x * blockDim.x + threadIdx.x;
    int stride = gridDim.x * blockDim.x;
    for (; i < n8; i += stride) {
        float4 f0 = ((const float4*)in)[(size_t)i * 2];
        float4 f1 = ((const float4*)in)[(size_t)i * 2 + 1];
        uint4 o;
        o.x = (u32)f2bf(f0.x) | ((u32)f2bf(f0.y) << 16);
        o.y = (u32)f2bf(f0.z) | ((u32)f2bf(f0.w) << 16);
        o.z = (u32)f2bf(f1.x) | ((u32)f2bf(f1.y) << 16);
        o.w = (u32)f2bf(f1.z) | ((u32)f2bf(f1.w) << 16);
        ((uint4*)out)[i] = o;
    }
}

// ---------------------------------------------------------------------------
// All weight transposes in one kernel. W[K][N] f32 -> Wt[rowoff+n][K] bf16.
// ---------------------------------------------------------------------------
__global__ __launch_bounds__(256)
void w_prep(const float* __restrict__ Wq, const float* __restrict__ Wk,
            const float* __restrict__ Wv, const float* __restrict__ Wm,
            const float* __restrict__ W1, const float* __restrict__ W2,
            u16* __restrict__ wqkvt, u16* __restrict__ wmt,
            u16* __restrict__ w1t, u16* __restrict__ w2t)
{
    __shared__ float tile[32][33];
    int bt = blockIdx.x;
    const float* src; u16* dst; int K, N, rowoff, tt;
    if (bt < 192)      { int w = bt >> 6; tt = bt & 63;
                         src = (w == 0) ? Wq : (w == 1) ? Wk : Wv;
                         dst = wqkvt; K = 256; N = 256; rowoff = w * 256; }
    else if (bt < 256) { tt = bt - 192; src = Wm; dst = wmt; K = 256; N = 256; rowoff = 0; }
    else if (bt < 512) { tt = bt - 256; src = W1; dst = w1t; K = 512; N = 512; rowoff = 0; }
    else               { tt = bt - 512; src = W2; dst = w2t; K = 512; N = 256; rowoff = 0; }
    int ntx = N >> 5;
    int n0 = (tt % ntx) * 32, k0 = (tt / ntx) * 32;
    int tx = threadIdx.x & 31, ty = threadIdx.x >> 5;
    #pragma unroll
    for (int i = 0; i < 32; i += 8)
        tile[ty + i][tx] = src[(size_t)(k0 + ty + i) * N + n0 + tx];
    __syncthreads();
    #pragma unroll
    for (int i = 0; i < 32; i += 8)
        dst[(size_t)(rowoff + n0 + ty + i) * K + k0 + tx] = f2bf(tile[tx][ty + i]);
}

// ---------------------------------------------------------------------------
// gemm128: bf16 MFMA GEMM, tile 128x128, BK=32, 4 waves (2x2), acc[4][4].
// True depth-1 async (2 raw barriers + counted vmcnt(4)); kc-XOR LDS swizzle.
// NEW: LDS-roundtrip epilogue -- frags go to the (dead) staging LDS with an
// XOR swizzle, then read back row-major for fully-coalesced 16B/lane stores
// (256 B contiguous per row). Fixes the 16-lines-per-store scatter of the
// direct C^T fragment stores.
// EPI: 0=none, 3=relu, 4=qkv split (q/k/v slabs, ldc fixed 256).
// ---------------------------------------------------------------------------
template<int EPI>
__global__ __launch_bounds__(256)
void gemm128(const u16* __restrict__ A1, const u16* __restrict__ A2,
             int KA, int sA1, int sA2,
             const u16* __restrict__ Bt, int ldb, int bstride,
             u16* __restrict__ C, int ldc, int K, float escale, int nx)
{
    __shared__ __align__(16) u16 smem[16384];   // 32 KB: As0,As1,Bs0,Bs1 / C-tile

    const int tid = threadIdx.x;
    const int nwg = gridDim.x;
    const int cpx = nwg >> 3;
    const int hb  = blockIdx.x;
    const int lb  = (hb & 7) * cpx + (hb >> 3);     // XCD-chunked
    const int m0 = (lb / nx) * 128;
    const int n0 = (lb % nx) * 128;
    const int w = tid >> 6, lane = tid & 63;
    const int wr = w >> 1, wc = w & 1;
    const int g = lane >> 4, r = lane & 15;

    Bt += (size_t)(m0 / L_SEQ) * bstride;

    f32x4 acc[4][4] = {};

    auto stage = [&](int kt, int buf) {
        u16* As_ = smem + buf * 4096;
        u16* Bs_ = smem + 8192 + buf * 4096;
        #pragma unroll
        for (int i = 0; i < 2; ++i) {
            int li  = i * 256 + tid;
            int row = li >> 2, kc = li & 3;
            int kcg = kc ^ ((row >> 1) & 3);        // pre-swizzled source
            int kg = kt * 32 + kcg * 8;
            const u16* Ap = (kg < KA) ? A1 : A2;
            int stride    = (kg < KA) ? sA1 : sA2;
            int col       = (kg < KA) ? kg  : kg - KA;
            gl_lds16(Ap + (size_t)(m0 + row) * stride + col, &As_[li * 8]);
            gl_lds16(Bt + (size_t)(n0 + row) * ldb + kt * 32 + kcg * 8,
                     &Bs_[li * 8]);
        }
    };

    const int kts = K / 32;
    const int gsw = g ^ ((r >> 1) & 3);             // swizzled k-chunk slot
    stage(0, 0);
    for (int kt = 0; kt < kts; ++kt) {
        const int cur = kt & 1;
        asm volatile("s_barrier" ::: "memory");     // A: buf^1 readers done
        if (kt + 1 < kts) {
            stage(kt + 1, cur ^ 1);
            asm volatile("s_waitcnt vmcnt(4)" ::: "memory");  // stage(kt) landed
        } else {
            asm volatile("s_waitcnt vmcnt(0)" ::: "memory");
        }
        asm volatile("s_barrier" ::: "memory");     // B: all waves' stage(kt) done

        const u16* Ar = smem + cur * 4096;
        const u16* Br = smem + 8192 + cur * 4096;
        s16x8 a[4], b[4];
        #pragma unroll
        for (int mi = 0; mi < 4; ++mi)
            a[mi] = *(const s16x8*)&Ar[(wr * 64 + mi * 16 + r) * 32 + gsw * 8];
        #pragma unroll
        for (int ni = 0; ni < 4; ++ni)
            b[ni] = *(const s16x8*)&Br[(wc * 64 + ni * 16 + r) * 32 + gsw * 8];
        __builtin_amdgcn_s_setprio(1);
        // swapped operands -> C^T frags: reg j = col (ni*16+g*4+j), row mi*16+r
        #pragma unroll
        for (int mi = 0; mi < 4; ++mi)
            #pragma unroll
            for (int ni = 0; ni < 4; ++ni)
                asm volatile("v_mfma_f32_16x16x32_bf16 %0, %1, %2, %0"
                             : "+v"(acc[mi][ni]) : "v"(b[ni]), "v"(a[mi]));
        __builtin_amdgcn_s_setprio(0);
    }

    asm volatile("s_nop 7");
    asm volatile("s_nop 7");

    // ---- LDS-roundtrip epilogue ----
    __syncthreads();                                // staging dead; reuse smem
    char* ct = (char*)smem;                         // [128][128] bf16, swizzled
    #pragma unroll
    for (int mi = 0; mi < 4; ++mi) {
        int rl = wr * 64 + mi * 16 + r;             // local row
        #pragma unroll
        for (int ni = 0; ni < 4; ++ni) {
            int cl = wc * 64 + ni * 16 + g * 4;     // local col
            int gc = n0 + cl;                       // global col (EPI4 select)
            ushort4 o;
            #pragma unroll
            for (int j = 0; j < 4; ++j) {
                float v = acc[mi][ni][j];
                if (EPI == 3)      v = (v > 0.f) ? v : 0.f;
                else if (EPI == 4) v = (gc < 512) ? ((v > 0.f) ? (v + 1.f) : __expf(v))
                                                  : v * escale;
                (&o.x)[j] = f2bf(v);
            }
            int byte = (rl * 256 + cl * 2) ^ ((rl & 7) << 4);
            *(ushort4*)(ct + byte) = o;
        }
    }
    __syncthreads();
    {
        const int rr = tid >> 4, ck = tid & 15;     // 16 rows x 16 chunks/iter
        u16* slab = C; int coff = n0;
        if (EPI == 4) {
            slab = (n0 < 256) ? C : (n0 < 512) ? C + SLAB_E : C + 2 * SLAB_E;
            coff = n0 & 255;
        }
        #pragma unroll
        for (int it = 0; it < 8; ++it) {
            int rl = it * 16 + rr;
            int byte = (rl * 256 + ck * 16) ^ ((rl & 7) << 4);
            uint4 val = *(const uint4*)(ct + byte);
            size_t row = (size_t)(m0 + rl);
            if (EPI == 4)
                *(uint4*)(slab + row * 256 + coff + ck * 8) = val;
            else
                *(uint4*)(C + row * (size_t)ldc + coff + ck * 8) = val;
        }
    }
}

// ---------------------------------------------------------------------------
// gemm_ln: 128x256-tile GEMM + fused LayerNorm epilogue, LDS-roundtrip
// coalesced stores. EPI: 5=LN->bf16 C; 6=LN+xres->f32 outf. N==256.
// ---------------------------------------------------------------------------
template<int EPI>
__global__ __launch_bounds__(256)
void gemm_ln(const u16* __restrict__ A1, const u16* __restrict__ A2,
             int KA, int sA1, int sA2,
             const u16* __restrict__ Bt, int ldb, int bstride,
             u16* __restrict__ C, int ldc, int K, float escale, int nx,
             const float* __restrict__ gw, const float* __restrict__ bw,
             const float* __restrict__ xres, float* __restrict__ outf)
{
    __shared__ __align__(16) u16 smem[24576];       // 48 KB: As(2x8KB), Bs(2x16KB)
    __shared__ float red[4][2][128];                // 4 KB (LN reduce)

    const int tid = threadIdx.x;
    const int nwg = gridDim.x;
    const int cpx = nwg >> 3;
    const int hb  = blockIdx.x;
    const int lb  = (hb & 7) * cpx + (hb >> 3);
    const int m0 = (lb / nx) * 128;
    const int n0 = (lb % nx) * 256;
    const int wc = tid >> 6;
    const int lane = tid & 63;
    const int g = lane >> 4, r = lane & 15;

    const u16* Btb = Bt + (size_t)(m0 / L_SEQ) * bstride;

    f32x4 acc[8][4] = {};

    auto stage = [&](int kt, int buf) {
        u16* As_ = smem + buf * 4096;
        u16* Bs_ = smem + 8192 + buf * 8192;
        #pragma unroll
        for (int i = 0; i < 2; ++i) {
            int li  = i * 256 + tid;
            int row = li >> 2, kc = li & 3;
            int kcg = kc ^ ((row >> 1) & 3);
            int kg = kt * 32 + kcg * 8;
            const u16* Ap = (kg < KA) ? A1 : A2;
            int stride    = (kg < KA) ? sA1 : sA2;
            int col       = (kg < KA) ? kg  : kg - KA;
            gl_lds16(Ap + (size_t)(m0 + row) * stride + col, &As_[li * 8]);
        }
        #pragma unroll
        for (int i = 0; i < 4; ++i) {
            int li  = i * 256 + tid;
            int row = li >> 2, kc = li & 3;
            int kcg = kc ^ ((row >> 1) & 3);
            gl_lds16(Btb + (size_t)(n0 + row) * ldb + kt * 32 + kcg * 8,
                     &Bs_[li * 8]);
        }
    };

    const int kts = K / 32;
    const int gsw = g ^ ((r >> 1) & 3);
    stage(0, 0);
    for (int kt = 0; kt < kts; ++kt) {
        const int cur = kt & 1;
        asm volatile("s_barrier" ::: "memory");
        if (kt + 1 < kts) {
            stage(kt + 1, cur ^ 1);
            asm volatile("s_waitcnt vmcnt(6)" ::: "memory");
        } else {
            asm volatile("s_waitcnt vmcnt(0)" ::: "memory");
        }
        asm volatile("s_barrier" ::: "memory");

        const u16* Ar = smem + cur * 4096;
        const u16* Br = smem + 8192 + cur * 8192;
        s16x8 b[4];
        #pragma unroll
        for (int ni = 0; ni < 4; ++ni)
            b[ni] = *(const s16x8*)&Br[(wc * 64 + ni * 16 + r) * 32 + gsw * 8];
        __builtin_amdgcn_s_setprio(1);
        #pragma unroll
        for (int mi = 0; mi < 8; ++mi) {
            s16x8 av = *(const s16x8*)&Ar[(mi * 16 + r) * 32 + gsw * 8];
            #pragma unroll
            for (int ni = 0; ni < 4; ++ni)
                asm volatile("v_mfma_f32_16x16x32_bf16 %0, %1, %2, %0"
                             : "+v"(acc[mi][ni]) : "v"(b[ni]), "v"(av));
        }
        __builtin_amdgcn_s_setprio(0);
    }

    asm volatile("s_nop 7");
    asm volatile("s_nop 7");

    // ---- LN stats (full rows in-block) ----
    #pragma unroll
    for (int mi = 0; mi < 8; ++mi) {
        float s = 0.f, s2 = 0.f;
        #pragma unroll
        for (int ni = 0; ni < 4; ++ni)
            #pragma unroll
            for (int j = 0; j < 4; ++j) {
                float v = acc[mi][ni][j];
                s += v; s2 += v * v;
            }
        s  += __shfl_xor(s, 16);  s  += __shfl_xor(s, 32);
        s2 += __shfl_xor(s2, 16); s2 += __shfl_xor(s2, 32);
        if (g == 0) {
            red[wc][0][mi * 16 + r] = s;
            red[wc][1][mi * 16 + r] = s2;
        }
    }
    __syncthreads();

    float4 gv[4], bv[4];
    #pragma unroll
    for (int ni = 0; ni < 4; ++ni) {
        int c = wc * 64 + ni * 16 + g * 4;
        gv[ni] = *(const float4*)&gw[c];
        bv[ni] = *(const float4*)&bw[c];
    }

    char* ct = (char*)smem;
    if (EPI == 5) {
        // two halves of 64 rows (32 KB bf16 each)
        #pragma unroll
        for (int h = 0; h < 2; ++h) {
            __syncthreads();
            #pragma unroll
            for (int mi2 = 0; mi2 < 4; ++mi2) {
                int mi = h * 4 + mi2;
                int rlg = mi * 16 + r;              // row in tile
                int rl = rlg - h * 64;              // row in half
                float S  = red[0][0][rlg] + red[1][0][rlg] + red[2][0][rlg] + red[3][0][rlg];
                float S2 = red[0][1][rlg] + red[1][1][rlg] + red[2][1][rlg] + red[3][1][rlg];
                float mu = S * (1.0f / 256.0f);
                float var = S2 * (1.0f / 256.0f) - mu * mu;
                float rstd = rsqrtf(var + 1e-5f);
                #pragma unroll
                for (int ni = 0; ni < 4; ++ni) {
                    int cl = wc * 64 + ni * 16 + g * 4;
                    ushort4 o;
                    o.x = f2bf((acc[mi][ni][0] - mu) * rstd * gv[ni].x + bv[ni].x);
                    o.y = f2bf((acc[mi][ni][1] - mu) * rstd * gv[ni].y + bv[ni].y);
                    o.z = f2bf((acc[mi][ni][2] - mu) * rstd * gv[ni].z + bv[ni].z);
                    o.w = f2bf((acc[mi][ni][3] - mu) * rstd * gv[ni].w + bv[ni].w);
                    int byte = (rl * 512 + cl * 2) ^ ((rl & 7) << 4);
                    *(ushort4*)(ct + byte) = o;
                }
            }
            __syncthreads();
            const int rr = tid >> 5, ck = tid & 31; // 8 rows x 32 chunks/iter
            #pragma unroll
            for (int it = 0; it < 8; ++it) {
                int rl = it * 8 + rr;
                int byte = (rl * 512 + ck * 16) ^ ((rl & 7) << 4);
                uint4 val = *(const uint4*)(ct + byte);
                size_t row = (size_t)(m0 + h * 64 + rl);
                *(uint4*)(C + row * 256 + ck * 8) = val;
            }
        }
    } else {
        // EPI 6: four quarters of 32 rows (32 KB f32 each)
        #pragma unroll
        for (int qd = 0; qd < 4; ++qd) {
            __syncthreads();
            #pragma unroll
            for (int mi2 = 0; mi2 < 2; ++mi2) {
                int mi = qd * 2 + mi2;
                int rlg = mi * 16 + r;
                int rl = rlg - qd * 32;
                float S  = red[0][0][rlg] + red[1][0][rlg] + red[2][0][rlg] + red[3][0][rlg];
                float S2 = red[0][1][rlg] + red[1][1][rlg] + red[2][1][rlg] + red[3][1][rlg];
                float mu = S * (1.0f / 256.0f);
                float var = S2 * (1.0f / 256.0f) - mu * mu;
                float rstd = rsqrtf(var + 1e-5f);
                #pragma unroll
                for (int ni = 0; ni < 4; ++ni) {
                    int cl = wc * 64 + ni * 16 + g * 4;
                    float4 o;
                    o.x = (acc[mi][ni][0] - mu) * rstd * gv[ni].x + bv[ni].x;
                    o.y = (acc[mi][ni][1] - mu) * rstd * gv[ni].y + bv[ni].y;
                    o.z = (acc[mi][ni][2] - mu) * rstd * gv[ni].z + bv[ni].z;
                    o.w = (acc[mi][ni][3] - mu) * rstd * gv[ni].w + bv[ni].w;
                    int byte = (rl * 1024 + cl * 4) ^ ((rl & 7) << 4);
                    *(float4*)(ct + byte) = o;
                }
            }
            __syncthreads();
            const int rr = tid >> 6, ck = tid & 63; // 4 rows x 64 chunks/iter
            #pragma unroll
            for (int it = 0; it < 8; ++it) {
                int rl = it * 4 + rr;
                int byte = (rl * 1024 + ck * 16) ^ ((rl & 7) << 4);
                float4 val = *(const float4*)(ct + byte);
                size_t row = (size_t)(m0 + qd * 32 + rl);
                float4 xv = *(const float4*)&xres[row * 256 + ck * 4];
                val.x += xv.x; val.y += xv.y; val.z += xv.z; val.w += xv.w;
                *(float4*)&outf[row * 256 + ck * 4] = val;
            }
        }
    }
}

// ---------------------------------------------------------------------------
// KV partial over L-chunks: KV[32][32] += K^T v ; Ksum[32] += K. f32 accum.
// ---------------------------------------------------------------------------
__global__ __launch_bounds__(256)
void kv_partial(const u16* __restrict__ Kf, const u16* __restrict__ Vf, int ld,
                float* __restrict__ part)
{
    int b  = blockIdx.x;
    int s  = b & (KV_SPLIT - 1);
    int nh = b / KV_SPLIT;
    int h  = nh & (N_HEAD - 1);
    int n  = nh / N_HEAD;
    int t  = threadIdx.x;

    __shared__ __align__(16) float Ks[32][D_H];
    __shared__ __align__(16) float Vs[32][D_H];

    const int d   = t >> 3;
    const int dv0 = (t & 7) * 4;
    const int lr  = t >> 3;
    const int lc  = (t & 7) * 4;
    const size_t base = ((size_t)n * L_SEQ) * ld + h * D_H;

    float a0 = 0, a1 = 0, a2 = 0, a3 = 0, asum = 0;
    const int CH = L_SEQ / KV_SPLIT;
    for (int l = s * CH; l < s * CH + CH; l += 32) {
        __syncthreads();
        uint2 ku = *(const uint2*)&Kf[base + (size_t)(l + lr) * ld + lc];
        uint2 vu = *(const uint2*)&Vf[base + (size_t)(l + lr) * ld + lc];
        Ks[lr][lc] = bf2f(ku.x & 0xffff); Ks[lr][lc + 1] = bf2f(ku.x >> 16);
        Ks[lr][lc + 2] = bf2f(ku.y & 0xffff); Ks[lr][lc + 3] = bf2f(ku.y >> 16);
        Vs[lr][lc] = bf2f(vu.x & 0xffff); Vs[lr][lc + 1] = bf2f(vu.x >> 16);
        Vs[lr][lc + 2] = bf2f(vu.y & 0xffff); Vs[lr][lc + 3] = bf2f(vu.y >> 16);
        __syncthreads();
        #pragma unroll
        for (int i = 0; i < 32; ++i) {
            float kv = Ks[i][d];
            float4 vv = *(const float4*)&Vs[i][dv0];
            a0 = fmaf(kv, vv.x, a0);
            a1 = fmaf(kv, vv.y, a1);
            a2 = fmaf(kv, vv.z, a2);
            a3 = fmaf(kv, vv.w, a3);
            asum += kv;
        }
    }
    float* p = part + (size_t)b * 1056;
    p[d * D_H + dv0 + 0] = a0;
    p[d * D_H + dv0 + 1] = a1;
    p[d * D_H + dv0 + 2] = a2;
    p[d * D_H + dv0 + 3] = a3;
    if ((t & 7) == 0) p[1024 + d] = asum;
}

__global__ __launch_bounds__(256)
void kv_final(const float* __restrict__ part, float* __restrict__ KV,
              float* __restrict__ Ksum)
{
    int nh = blockIdx.x;
    int t  = threadIdx.x;
    float ax = 0, ay = 0, az = 0, aw = 0, ssum = 0;
    const float* p0 = part + (size_t)nh * KV_SPLIT * 1056;
    for (int s = 0; s < KV_SPLIT; ++s) {
        const float* p = p0 + (size_t)s * 1056;
        float4 v = *(const float4*)&p[t * 4];
        ax += v.x; ay += v.y; az += v.z; aw += v.w;
        if (t < D_H) ssum += p[1024 + t];
    }
    float4 o = make_float4(ax, ay, az, aw);
    *(float4*)&KV[(size_t)nh * 1024 + t * 4] = o;
    if (t < D_H) Ksum[nh * D_H + t] = ssum;
}

// ---------------------------------------------------------------------------
// bdr: BDmat rows in Bt layout for the BDW GEMM.
// ---------------------------------------------------------------------------
__global__ __launch_bounds__(256)
void bdr_build(const float* __restrict__ KV, u16* __restrict__ bdr)
{
    int idx = blockIdx.x * 256 + threadIdx.x;      // 0 .. 4*256*256-1
    int b = idx >> 16;
    int n = (idx >> 8) & 255;
    int k = idx & 255;
    float v = ((n >> 5) == (k >> 5))
            ? KV[(((size_t)b * N_HEAD + (n >> 5)) * D_H + (n & 31)) * D_H + (k & 31)]
            : 0.f;
    bdr[idx] = f2bf(v);
}

// ---------------------------------------------------------------------------
// attn_z: q[tok][c] *= L / (q[tok] . Ksum_head(c) + eps), in place.
// ---------------------------------------------------------------------------
#define NT_TOK 32
__global__ __launch_bounds__(256)
void attn_z(u16* __restrict__ q, const float* __restrict__ Ksum)
{
    const int t = threadIdx.x;
    const int w = t >> 6, lane = t & 63;
    const int tok0 = blockIdx.x * NT_TOK;
    const int n = tok0 / L_SEQ;
    float4 ks = *(const float4*)&Ksum[n * C_DIM + lane * 4];

    for (int i = 0; i < NT_TOK; i += 4) {
        int tok = tok0 + i + w;
        u16* qp = q + (size_t)tok * C_DIM + lane * 4;
        uint2 qu = *(const uint2*)qp;
        float q0 = bf2f(qu.x & 0xffff), q1 = bf2f(qu.x >> 16);
        float q2 = bf2f(qu.y & 0xffff), q3 = bf2f(qu.y >> 16);
        float p = q0 * ks.x + q1 * ks.y + q2 * ks.z + q3 * ks.w;
        p += __shfl_xor(p, 1);
        p += __shfl_xor(p, 2);
        p += __shfl_xor(p, 4);
        float z = (float)L_SEQ / (p + 1e-6f);
        uint2 o;
        o.x = (u32)f2bf(q0 * z) | ((u32)f2bf(q1 * z) << 16);
        o.y = (u32)f2bf(q2 * z) | ((u32)f2bf(q3 * z) << 16);
        *(uint2*)qp = o;
    }
}

// ---------------------------------------------------------------------------
extern "C" void kernel_launch(void* const* d_in, const int* in_sizes, int n_in,
                              void* d_out, int out_size, void* d_ws, size_t ws_size,
                              hipStream_t stream)
{
    const float* x  = (const float*)d_in[0];
    const float* Wq = (const float*)d_in[1];
    const float* Wk = (const float*)d_in[2];
    const float* Wv = (const float*)d_in[3];
    const float* Wm = (const float*)d_in[4];
    const float* W1 = (const float*)d_in[5];
    const float* W2 = (const float*)d_in[6];
    const float* g1 = (const float*)d_in[7];
    const float* b1 = (const float*)d_in[8];
    const float* g2 = (const float*)d_in[9];
    const float* b2 = (const float*)d_in[10];
    float* out = (float*)d_out;

    u16* xb  = (u16*)d_ws;          // slab 0
    u16* q   = xb + SLAB_E;         // slab 1  (q' after attn_z; h-lo after)
    u16* k   = q + SLAB_E;          // slab 2  (dead after kv -> h-hi)
    u16* v   = k + SLAB_E;          // slab 3  (dead after kv)
    u16* ln1 = v + SLAB_E;          // slab 4
    u16* h   = q;                   // spans q..k (M x 512), q'/k dead by then
    // weights (transposed bf16) + small buffers
    u16* wqkvt = ln1 + SLAB_E;             // 768*256
    u16* wmt   = wqkvt + 768 * 256;        // 256*256
    u16* w1t   = wmt + 256 * 256;          // 512*512
    u16* w2t   = w1t + 512 * 512;          // 256*512
    u16* bdr   = w2t + 256 * 512;          // 4*256*256
    u16* bdwt  = bdr + (size_t)N_BATCH * 256 * 256;   // 4*256*256, [c][b*256+k]
    float* KV   = (float*)(bdwt + (size_t)N_BATCH * 256 * 256);
    float* Ksum = KV + (size_t)N_BATCH * N_HEAD * D_H * D_H;
    float* part = Ksum + (size_t)N_BATCH * N_HEAD * D_H;

    dim3 blk(256);
    const float invL = 1.0f / (float)L_SEQ;

    // ---- prep ----
    f32_to_bf16_k<<<2048, blk, 0, stream>>>(x, xb, (int)(SLAB_E / 8));
    w_prep<<<640, blk, 0, stream>>>(Wq, Wk, Wv, Wm, W1, W2, wqkvt, wmt, w1t, w2t);

    // ---- fused QKV projection -> dense q,k,v slabs (128x128 tiles, nx=6) ----
    gemm128<4><<<(M_ROWS / 128) * 6, blk, 0, stream>>>(
        xb, xb, 256, 256, 256, wqkvt, 256, 0, q, 256, 256, invL, 6);

    // ---- KV reduction ----
    kv_partial<<<N_BATCH * N_HEAD * KV_SPLIT, blk, 0, stream>>>(k, v, 256, part);
    kv_final<<<N_BATCH * N_HEAD, blk, 0, stream>>>(part, KV, Ksum);

    // ---- BDW = BD @ Wm (tiny GEMM), bdwt[c][b*256+k] ----
    bdr_build<<<(N_BATCH * 256 * 256) / 256, blk, 0, stream>>>(KV, bdr);
    gemm128<0><<<16, blk, 0, stream>>>(
        wmt, wmt, 256, 256, 256, bdr, 256, 0, bdwt, 1024, 256, 1.f, 8);

    // ---- q' = q * z (in place) ----
    attn_z<<<M_ROWS / NT_TOK, blk, 0, stream>>>(q, Ksum);

    // ---- ln1 = LN(q' @ BDW_b; g1,b1)  (fused epilogue) ----
    gemm_ln<5><<<M_ROWS / 128, blk, 0, stream>>>(
        q, q, 256, 256, 256, bdwt, 1024, 256, ln1, 256, 256, 1.f, 1,
        g1, b1, nullptr, nullptr);

    // ---- h = relu(concat(xb, ln1) @ W1)  (128x128 tiles, nx=4) ----
    gemm128<3><<<(M_ROWS / 128) * 4, blk, 0, stream>>>(
        xb, ln1, 256, 256, 256, w1t, 512, 0, h, 512, 512, 1.f, 4);

    // ---- out = x + LN(h @ W2; g2,b2)  (fused epilogue, f32 out) ----
    gemm_ln<6><<<M_ROWS / 128, blk, 0, stream>>>(
        h, h, 512, 512, 512, w2t, 512, 0, nullptr, 256, 512, 1.f, 1,
        g2, b2, x, out);
}

// Round 13
// 232.161 us; speedup vs baseline: 1.5385x; 1.0236x over previous
//
#include <hip/hip_runtime.h>
#include <hip/hip_bf16.h>
#include <math.h>

#define L_SEQ   16384
#define C_DIM   256
#define N_BATCH 4
#define N_HEAD  8
#define D_H     32
#define M_ROWS  (N_BATCH * L_SEQ)   // 65536
#define KV_SPLIT 64
#define SLAB_E  ((size_t)M_ROWS * C_DIM)   // 16,777,216 elems

typedef unsigned short u16;
typedef unsigned int   u32;
typedef short s16x8 __attribute__((ext_vector_type(8)));
typedef float f32x4 __attribute__((ext_vector_type(4)));

// ---- bf16 helpers (bit-exact bf16->f32; RNE f32->bf16) ----------------------
__device__ __forceinline__ float bf2f(u32 lo16) { return __uint_as_float(lo16 << 16); }
__device__ __forceinline__ u16 f2bf(float f) {
    u32 u = __float_as_uint(f);
    u32 rb = ((u >> 16) & 1u) + 0x7fffu;
    return (u16)((u + rb) >> 16);
}

// ---- async global->LDS, 16B per lane ---------------------------------------
__device__ __forceinline__ void gl_lds16(const u16* g, u16* l) {
    __builtin_amdgcn_global_load_lds(
        (__attribute__((address_space(1))) void*)g,
        (__attribute__((address_space(3))) void*)l, 16, 0, 0);
}

// ---------------------------------------------------------------------------
// prep_all: blocks [0,2048) = f32->bf16 convert of x (grid-stride);
// blocks [2048,2688) = weight transposes W[K][N] f32 -> Wt[rowoff+n][K] bf16.
// ---------------------------------------------------------------------------
__global__ __launch_bounds__(256)
void prep_all(const float* __restrict__ x, u16* __restrict__ xb, int n8,
              const float* __restrict__ Wq, const float* __restrict__ Wk,
              const float* __restrict__ Wv, const float* __restrict__ Wm,
              const float* __restrict__ W1, const float* __restrict__ W2,
              u16* __restrict__ wqkvt, u16* __restrict__ wmt,
              u16* __restrict__ w1t, u16* __restrict__ w2t)
{
    __shared__ float tile[32][33];
    int bt = blockIdx.x;
    if (bt < 2048) {
        int i = bt * 256 + threadIdx.x;
        int stride = 2048 * 256;
        for (; i < n8; i += stride) {
            float4 f0 = ((const float4*)x)[(size_t)i * 2];
            float4 f1 = ((const float4*)x)[(size_t)i * 2 + 1];
            uint4 o;
            o.x = (u32)f2bf(f0.x) | ((u32)f2bf(f0.y) << 16);
            o.y = (u32)f2bf(f0.z) | ((u32)f2bf(f0.w) << 16);
            o.z = (u32)f2bf(f1.x) | ((u32)f2bf(f1.y) << 16);
            o.w = (u32)f2bf(f1.z) | ((u32)f2bf(f1.w) << 16);
            ((uint4*)xb)[i] = o;
        }
        return;
    }
    bt -= 2048;
    const float* src; u16* dst; int K, N, rowoff, tt;
    if (bt < 192)      { int w = bt >> 6; tt = bt & 63;
                         src = (w == 0) ? Wq : (w == 1) ? Wk : Wv;
                         dst = wqkvt; K = 256; N = 256; rowoff = w * 256; }
    else if (bt < 256) { tt = bt - 192; src = Wm; dst = wmt; K = 256; N = 256; rowoff = 0; }
    else if (bt < 512) { tt = bt - 256; src = W1; dst = w1t; K = 512; N = 512; rowoff = 0; }
    else               { tt = bt - 512; src = W2; dst = w2t; K = 512; N = 256; rowoff = 0; }
    int ntx = N >> 5;
    int n0 = (tt % ntx) * 32, k0 = (tt / ntx) * 32;
    int tx = threadIdx.x & 31, ty = threadIdx.x >> 5;
    #pragma unroll
    for (int i = 0; i < 32; i += 8)
        tile[ty + i][tx] = src[(size_t)(k0 + ty + i) * N + n0 + tx];
    __syncthreads();
    #pragma unroll
    for (int i = 0; i < 32; i += 8)
        dst[(size_t)(rowoff + n0 + ty + i) * K + k0 + tx] = f2bf(tile[tx][ty + i]);
}

// ---------------------------------------------------------------------------
// gemm128: bf16 MFMA GEMM, tile 128x128, BK=32, 4 waves (2x2), acc[4][4].
// True depth-1 async (2 raw barriers + counted vmcnt(4)); kc-XOR LDS swizzle;
// LDS-roundtrip coalesced epilogue (R11-proven); hoisted staging addresses.
// EPI: 0=none, 3=relu, 4=qkv split (q/k/v slabs, ldc fixed 256).
// ---------------------------------------------------------------------------
template<int EPI>
__global__ __launch_bounds__(256)
void gemm128(const u16* __restrict__ A1, const u16* __restrict__ A2,
             int KA, int sA1, int sA2,
             const u16* __restrict__ Bt, int ldb, int bstride,
             u16* __restrict__ C, int ldc, int K, float escale, int nx)
{
    __shared__ __align__(16) u16 smem[16384];   // 32 KB: As0,As1,Bs0,Bs1 / C-tile

    const int tid = threadIdx.x;
    const int nwg = gridDim.x;
    const int cpx = nwg >> 3;
    const int hb  = blockIdx.x;
    const int lb  = (hb & 7) * cpx + (hb >> 3);     // XCD-chunked
    const int m0 = (lb / nx) * 128;
    const int n0 = (lb % nx) * 128;
    const int w = tid >> 6, lane = tid & 63;
    const int wr = w >> 1, wc = w & 1;
    const int g = lane >> 4, r = lane & 15;

    Bt += (size_t)(m0 / L_SEQ) * bstride;

    // hoisted per-thread staging addresses (swizzled col folded into base)
    const u16 *pA1[2], *pA2[2], *pB[2];
    int loff[2];
    #pragma unroll
    for (int i = 0; i < 2; ++i) {
        int li  = i * 256 + tid;
        int row = li >> 2, kc = li & 3;
        int kcg = kc ^ ((row >> 1) & 3);
        pA1[i] = A1 + (size_t)(m0 + row) * sA1 + kcg * 8;
        pA2[i] = A2 + (size_t)(m0 + row) * sA2 + kcg * 8 - KA;
        pB[i]  = Bt + (size_t)(n0 + row) * ldb + kcg * 8;
        loff[i] = li * 8;
    }

    f32x4 acc[4][4] = {};

    auto stage = [&](int kt, int buf) {
        u16* As_ = smem + buf * 4096;
        u16* Bs_ = smem + 8192 + buf * 4096;
        const int ko = kt * 32;
        #pragma unroll
        for (int i = 0; i < 2; ++i) {
            const u16* Ap = ((ko < KA) ? pA1[i] : pA2[i]) + ko;
            gl_lds16(Ap, &As_[loff[i]]);
            gl_lds16(pB[i] + ko, &Bs_[loff[i]]);
        }
    };

    const int kts = K / 32;
    const int gsw = g ^ ((r >> 1) & 3);             // swizzled k-chunk slot
    stage(0, 0);
    for (int kt = 0; kt < kts; ++kt) {
        const int cur = kt & 1;
        asm volatile("s_barrier" ::: "memory");     // A: buf^1 readers done
        if (kt + 1 < kts) {
            stage(kt + 1, cur ^ 1);
            asm volatile("s_waitcnt vmcnt(4)" ::: "memory");  // stage(kt) landed
        } else {
            asm volatile("s_waitcnt vmcnt(0)" ::: "memory");
        }
        asm volatile("s_barrier" ::: "memory");     // B: all waves' stage(kt) done

        const u16* Ar = smem + cur * 4096;
        const u16* Br = smem + 8192 + cur * 4096;
        s16x8 a[4], b[4];
        #pragma unroll
        for (int mi = 0; mi < 4; ++mi)
            a[mi] = *(const s16x8*)&Ar[(wr * 64 + mi * 16 + r) * 32 + gsw * 8];
        #pragma unroll
        for (int ni = 0; ni < 4; ++ni)
            b[ni] = *(const s16x8*)&Br[(wc * 64 + ni * 16 + r) * 32 + gsw * 8];
        __builtin_amdgcn_s_setprio(1);
        // swapped operands -> C^T frags: reg j = col (ni*16+g*4+j), row mi*16+r
        #pragma unroll
        for (int mi = 0; mi < 4; ++mi)
            #pragma unroll
            for (int ni = 0; ni < 4; ++ni)
                asm volatile("v_mfma_f32_16x16x32_bf16 %0, %1, %2, %0"
                             : "+v"(acc[mi][ni]) : "v"(b[ni]), "v"(a[mi]));
        __builtin_amdgcn_s_setprio(0);
    }

    asm volatile("s_nop 7");
    asm volatile("s_nop 7");

    // ---- LDS-roundtrip epilogue ----
    __syncthreads();                                // staging dead; reuse smem
    char* ct = (char*)smem;                         // [128][128] bf16, swizzled
    #pragma unroll
    for (int mi = 0; mi < 4; ++mi) {
        int rl = wr * 64 + mi * 16 + r;             // local row
        #pragma unroll
        for (int ni = 0; ni < 4; ++ni) {
            int cl = wc * 64 + ni * 16 + g * 4;     // local col
            int gc = n0 + cl;                       // global col (EPI4 select)
            ushort4 o;
            #pragma unroll
            for (int j = 0; j < 4; ++j) {
                float v = acc[mi][ni][j];
                if (EPI == 3)      v = (v > 0.f) ? v : 0.f;
                else if (EPI == 4) v = (gc < 512) ? ((v > 0.f) ? (v + 1.f) : __expf(v))
                                                  : v * escale;
                (&o.x)[j] = f2bf(v);
            }
            int byte = (rl * 256 + cl * 2) ^ ((rl & 7) << 4);
            *(ushort4*)(ct + byte) = o;
        }
    }
    __syncthreads();
    {
        const int rr = tid >> 4, ck = tid & 15;     // 16 rows x 16 chunks/iter
        u16* slab = C; int coff = n0;
        if (EPI == 4) {
            slab = (n0 < 256) ? C : (n0 < 512) ? C + SLAB_E : C + 2 * SLAB_E;
            coff = n0 & 255;
        }
        #pragma unroll
        for (int it = 0; it < 8; ++it) {
            int rl = it * 16 + rr;
            int byte = (rl * 256 + ck * 16) ^ ((rl & 7) << 4);
            uint4 val = *(const uint4*)(ct + byte);
            size_t row = (size_t)(m0 + rl);
            if (EPI == 4)
                *(uint4*)(slab + row * 256 + coff + ck * 8) = val;
            else
                *(uint4*)(C + row * (size_t)ldc + coff + ck * 8) = val;
        }
    }
}

// ---------------------------------------------------------------------------
// gemm_ln: 128x256-tile GEMM + fused LayerNorm epilogue, LDS-roundtrip
// coalesced stores, hoisted staging. EPI: 5=LN->bf16 C; 6=LN+xres->f32 outf.
// ---------------------------------------------------------------------------
template<int EPI>
__global__ __launch_bounds__(256)
void gemm_ln(const u16* __restrict__ A1, const u16* __restrict__ A2,
             int KA, int sA1, int sA2,
             const u16* __restrict__ Bt, int ldb, int bstride,
             u16* __restrict__ C, int ldc, int K, float escale, int nx,
             const float* __restrict__ gw, const float* __restrict__ bw,
             const float* __restrict__ xres, float* __restrict__ outf)
{
    __shared__ __align__(16) u16 smem[24576];       // 48 KB: As(2x8KB), Bs(2x16KB)
    __shared__ float red[4][2][128];                // 4 KB (LN reduce)

    const int tid = threadIdx.x;
    const int nwg = gridDim.x;
    const int cpx = nwg >> 3;
    const int hb  = blockIdx.x;
    const int lb  = (hb & 7) * cpx + (hb >> 3);
    const int m0 = (lb / nx) * 128;
    const int n0 = (lb % nx) * 256;
    const int wc = tid >> 6;
    const int lane = tid & 63;
    const int g = lane >> 4, r = lane & 15;

    const u16* Btb = Bt + (size_t)(m0 / L_SEQ) * bstride;

    // hoisted staging addresses
    const u16 *pA1[2], *pA2[2], *pB[4];
    int loffA[2], loffB[4];
    #pragma unroll
    for (int i = 0; i < 2; ++i) {
        int li  = i * 256 + tid;
        int row = li >> 2, kc = li & 3;
        int kcg = kc ^ ((row >> 1) & 3);
        pA1[i] = A1 + (size_t)(m0 + row) * sA1 + kcg * 8;
        pA2[i] = A2 + (size_t)(m0 + row) * sA2 + kcg * 8 - KA;
        loffA[i] = li * 8;
    }
    #pragma unroll
    for (int i = 0; i < 4; ++i) {
        int li  = i * 256 + tid;
        int row = li >> 2, kc = li & 3;
        int kcg = kc ^ ((row >> 1) & 3);
        pB[i] = Btb + (size_t)(n0 + row) * ldb + kcg * 8;
        loffB[i] = li * 8;
    }

    f32x4 acc[8][4] = {};

    auto stage = [&](int kt, int buf) {
        u16* As_ = smem + buf * 4096;
        u16* Bs_ = smem + 8192 + buf * 8192;
        const int ko = kt * 32;
        #pragma unroll
        for (int i = 0; i < 2; ++i) {
            const u16* Ap = ((ko < KA) ? pA1[i] : pA2[i]) + ko;
            gl_lds16(Ap, &As_[loffA[i]]);
        }
        #pragma unroll
        for (int i = 0; i < 4; ++i)
            gl_lds16(pB[i] + ko, &Bs_[loffB[i]]);
    };

    const int kts = K / 32;
    const int gsw = g ^ ((r >> 1) & 3);
    stage(0, 0);
    for (int kt = 0; kt < kts; ++kt) {
        const int cur = kt & 1;
        asm volatile("s_barrier" ::: "memory");
        if (kt + 1 < kts) {
            stage(kt + 1, cur ^ 1);
            asm volatile("s_waitcnt vmcnt(6)" ::: "memory");
        } else {
            asm volatile("s_waitcnt vmcnt(0)" ::: "memory");
        }
        asm volatile("s_barrier" ::: "memory");

        const u16* Ar = smem + cur * 4096;
        const u16* Br = smem + 8192 + cur * 8192;
        s16x8 b[4];
        #pragma unroll
        for (int ni = 0; ni < 4; ++ni)
            b[ni] = *(const s16x8*)&Br[(wc * 64 + ni * 16 + r) * 32 + gsw * 8];
        __builtin_amdgcn_s_setprio(1);
        #pragma unroll
        for (int mi = 0; mi < 8; ++mi) {
            s16x8 av = *(const s16x8*)&Ar[(mi * 16 + r) * 32 + gsw * 8];
            #pragma unroll
            for (int ni = 0; ni < 4; ++ni)
                asm volatile("v_mfma_f32_16x16x32_bf16 %0, %1, %2, %0"
                             : "+v"(acc[mi][ni]) : "v"(b[ni]), "v"(av));
        }
        __builtin_amdgcn_s_setprio(0);
    }

    asm volatile("s_nop 7");
    asm volatile("s_nop 7");

    // ---- LN stats (full rows in-block) ----
    #pragma unroll
    for (int mi = 0; mi < 8; ++mi) {
        float s = 0.f, s2 = 0.f;
        #pragma unroll
        for (int ni = 0; ni < 4; ++ni)
            #pragma unroll
            for (int j = 0; j < 4; ++j) {
                float v = acc[mi][ni][j];
                s += v; s2 += v * v;
            }
        s  += __shfl_xor(s, 16);  s  += __shfl_xor(s, 32);
        s2 += __shfl_xor(s2, 16); s2 += __shfl_xor(s2, 32);
        if (g == 0) {
            red[wc][0][mi * 16 + r] = s;
            red[wc][1][mi * 16 + r] = s2;
        }
    }
    __syncthreads();

    float4 gv[4], bv[4];
    #pragma unroll
    for (int ni = 0; ni < 4; ++ni) {
        int c = wc * 64 + ni * 16 + g * 4;
        gv[ni] = *(const float4*)&gw[c];
        bv[ni] = *(const float4*)&bw[c];
    }

    char* ct = (char*)smem;
    if (EPI == 5) {
        // two halves of 64 rows (32 KB bf16 each)
        #pragma unroll
        for (int h = 0; h < 2; ++h) {
            __syncthreads();
            #pragma unroll
            for (int mi2 = 0; mi2 < 4; ++mi2) {
                int mi = h * 4 + mi2;
                int rlg = mi * 16 + r;              // row in tile
                int rl = rlg - h * 64;              // row in half
                float S  = red[0][0][rlg] + red[1][0][rlg] + red[2][0][rlg] + red[3][0][rlg];
                float S2 = red[0][1][rlg] + red[1][1][rlg] + red[2][1][rlg] + red[3][1][rlg];
                float mu = S * (1.0f / 256.0f);
                float var = S2 * (1.0f / 256.0f) - mu * mu;
                float rstd = rsqrtf(var + 1e-5f);
                #pragma unroll
                for (int ni = 0; ni < 4; ++ni) {
                    int cl = wc * 64 + ni * 16 + g * 4;
                    ushort4 o;
                    o.x = f2bf((acc[mi][ni][0] - mu) * rstd * gv[ni].x + bv[ni].x);
                    o.y = f2bf((acc[mi][ni][1] - mu) * rstd * gv[ni].y + bv[ni].y);
                    o.z = f2bf((acc[mi][ni][2] - mu) * rstd * gv[ni].z + bv[ni].z);
                    o.w = f2bf((acc[mi][ni][3] - mu) * rstd * gv[ni].w + bv[ni].w);
                    int byte = (rl * 512 + cl * 2) ^ ((rl & 7) << 4);
                    *(ushort4*)(ct + byte) = o;
                }
            }
            __syncthreads();
            const int rr = tid >> 5, ck = tid & 31; // 8 rows x 32 chunks/iter
            #pragma unroll
            for (int it = 0; it < 8; ++it) {
                int rl = it * 8 + rr;
                int byte = (rl * 512 + ck * 16) ^ ((rl & 7) << 4);
                uint4 val = *(const uint4*)(ct + byte);
                size_t row = (size_t)(m0 + h * 64 + rl);
                *(uint4*)(C + row * 256 + ck * 8) = val;
            }
        }
    } else {
        // EPI 6: four quarters of 32 rows (32 KB f32 each)
        #pragma unroll
        for (int qd = 0; qd < 4; ++qd) {
            __syncthreads();
            #pragma unroll
            for (int mi2 = 0; mi2 < 2; ++mi2) {
                int mi = qd * 2 + mi2;
                int rlg = mi * 16 + r;
                int rl = rlg - qd * 32;
                float S  = red[0][0][rlg] + red[1][0][rlg] + red[2][0][rlg] + red[3][0][rlg];
                float S2 = red[0][1][rlg] + red[1][1][rlg] + red[2][1][rlg] + red[3][1][rlg];
                float mu = S * (1.0f / 256.0f);
                float var = S2 * (1.0f / 256.0f) - mu * mu;
                float rstd = rsqrtf(var + 1e-5f);
                #pragma unroll
                for (int ni = 0; ni < 4; ++ni) {
                    int cl = wc * 64 + ni * 16 + g * 4;
                    float4 o;
                    o.x = (acc[mi][ni][0] - mu) * rstd * gv[ni].x + bv[ni].x;
                    o.y = (acc[mi][ni][1] - mu) * rstd * gv[ni].y + bv[ni].y;
                    o.z = (acc[mi][ni][2] - mu) * rstd * gv[ni].z + bv[ni].z;
                    o.w = (acc[mi][ni][3] - mu) * rstd * gv[ni].w + bv[ni].w;
                    int byte = (rl * 1024 + cl * 4) ^ ((rl & 7) << 4);
                    *(float4*)(ct + byte) = o;
                }
            }
            __syncthreads();
            const int rr = tid >> 6, ck = tid & 63; // 4 rows x 64 chunks/iter
            #pragma unroll
            for (int it = 0; it < 8; ++it) {
                int rl = it * 4 + rr;
                int byte = (rl * 1024 + ck * 16) ^ ((rl & 7) << 4);
                float4 val = *(const float4*)(ct + byte);
                size_t row = (size_t)(m0 + qd * 32 + rl);
                float4 xv = *(const float4*)&xres[row * 256 + ck * 4];
                val.x += xv.x; val.y += xv.y; val.z += xv.z; val.w += xv.w;
                *(float4*)&outf[row * 256 + ck * 4] = val;
            }
        }
    }
}

// ---------------------------------------------------------------------------
// KV partial over L-chunks: KV[32][32] += K^T v ; Ksum[32] += K. f32 accum.
// ---------------------------------------------------------------------------
__global__ __launch_bounds__(256)
void kv_partial(const u16* __restrict__ Kf, const u16* __restrict__ Vf, int ld,
                float* __restrict__ part)
{
    int b  = blockIdx.x;
    int s  = b & (KV_SPLIT - 1);
    int nh = b / KV_SPLIT;
    int h  = nh & (N_HEAD - 1);
    int n  = nh / N_HEAD;
    int t  = threadIdx.x;

    __shared__ __align__(16) float Ks[32][D_H];
    __shared__ __align__(16) float Vs[32][D_H];

    const int d   = t >> 3;
    const int dv0 = (t & 7) * 4;
    const int lr  = t >> 3;
    const int lc  = (t & 7) * 4;
    const size_t base = ((size_t)n * L_SEQ) * ld + h * D_H;

    float a0 = 0, a1 = 0, a2 = 0, a3 = 0, asum = 0;
    const int CH = L_SEQ / KV_SPLIT;
    for (int l = s * CH; l < s * CH + CH; l += 32) {
        __syncthreads();
        uint2 ku = *(const uint2*)&Kf[base + (size_t)(l + lr) * ld + lc];
        uint2 vu = *(const uint2*)&Vf[base + (size_t)(l + lr) * ld + lc];
        Ks[lr][lc] = bf2f(ku.x & 0xffff); Ks[lr][lc + 1] = bf2f(ku.x >> 16);
        Ks[lr][lc + 2] = bf2f(ku.y & 0xffff); Ks[lr][lc + 3] = bf2f(ku.y >> 16);
        Vs[lr][lc] = bf2f(vu.x & 0xffff); Vs[lr][lc + 1] = bf2f(vu.x >> 16);
        Vs[lr][lc + 2] = bf2f(vu.y & 0xffff); Vs[lr][lc + 3] = bf2f(vu.y >> 16);
        __syncthreads();
        #pragma unroll
        for (int i = 0; i < 32; ++i) {
            float kv = Ks[i][d];
            float4 vv = *(const float4*)&Vs[i][dv0];
            a0 = fmaf(kv, vv.x, a0);
            a1 = fmaf(kv, vv.y, a1);
            a2 = fmaf(kv, vv.z, a2);
            a3 = fmaf(kv, vv.w, a3);
            asum += kv;
        }
    }
    float* p = part + (size_t)b * 1056;
    p[d * D_H + dv0 + 0] = a0;
    p[d * D_H + dv0 + 1] = a1;
    p[d * D_H + dv0 + 2] = a2;
    p[d * D_H + dv0 + 3] = a3;
    if ((t & 7) == 0) p[1024 + d] = asum;
}

// ---------------------------------------------------------------------------
// kv_final + bdr build fused: per (n,h) block reduces the partials, writes
// Ksum, and emits its 32 rows of the block-diagonal bdr (values + zeros).
// bdr[b*256 + n][k] = (n>>5==k>>5) ? KVs[n&31][k&31] : 0   (KVs = [d][dv])
// ---------------------------------------------------------------------------
__global__ __launch_bounds__(256)
void kv_final(const float* __restrict__ part, float* __restrict__ Ksum,
              u16* __restrict__ bdr)
{
    __shared__ float KVs[D_H][D_H];   // [d][dv]
    int nh = blockIdx.x;              // n*8 + h
    int h  = nh & (N_HEAD - 1);
    int n  = nh / N_HEAD;
    int t  = threadIdx.x;

    float ax = 0, ay = 0, az = 0, aw = 0, ssum = 0;
    const float* p0 = part + (size_t)nh * KV_SPLIT * 1056;
    for (int s = 0; s < KV_SPLIT; ++s) {
        const float* p = p0 + (size_t)s * 1056;
        float4 v = *(const float4*)&p[t * 4];
        ax += v.x; ay += v.y; az += v.z; aw += v.w;
        if (t < D_H) ssum += p[1024 + t];
    }
    const int d = t >> 3, dv0 = (t & 7) * 4;
    KVs[d][dv0] = ax; KVs[d][dv0 + 1] = ay; KVs[d][dv0 + 2] = az; KVs[d][dv0 + 3] = aw;
    if (t < D_H) Ksum[nh * D_H + t] = ssum;
    __syncthreads();

    // this block owns bdr rows (n*256 + h*32 + rr), rr in [0,32); 256 cols.
    // diagonal block value at (row rr, col j) = KVs[rr][j]  [FIXED: was KVs[j][rr]]
    const int rr = t >> 3;            // row within head block (= d index)
    const int c0 = (t & 7) * 32;      // col group
    u16* dst = bdr + ((size_t)n * 256 + h * 32 + rr) * 256 + c0;
    if (c0 == h * 32) {
        #pragma unroll
        for (int j = 0; j < 32; j += 4) {
            float4 vv = *(const float4*)&KVs[rr][j];
            ushort4 o;
            o.x = f2bf(vv.x); o.y = f2bf(vv.y); o.z = f2bf(vv.z); o.w = f2bf(vv.w);
            *(ushort4*)(dst + j) = o;
        }
    } else {
        uint4 z = make_uint4(0, 0, 0, 0);
        #pragma unroll
        for (int j = 0; j < 32; j += 8)
            *(uint4*)(dst + j) = z;
    }
}

// ---------------------------------------------------------------------------
// attn_z: q[tok][c] *= L / (q[tok] . Ksum_head(c) + eps), in place.
// ---------------------------------------------------------------------------
#define NT_TOK 32
__global__ __launch_bounds__(256)
void attn_z(u16* __restrict__ q, const float* __restrict__ Ksum)
{
    const int t = threadIdx.x;
    const int w = t >> 6, lane = t & 63;
    const int tok0 = blockIdx.x * NT_TOK;
    const int n = tok0 / L_SEQ;
    float4 ks = *(const float4*)&Ksum[n * C_DIM + lane * 4];

    for (int i = 0; i < NT_TOK; i += 4) {
        int tok = tok0 + i + w;
        u16* qp = q + (size_t)tok * C_DIM + lane * 4;
        uint2 qu = *(const uint2*)qp;
        float q0 = bf2f(qu.x & 0xffff), q1 = bf2f(qu.x >> 16);
        float q2 = bf2f(qu.y & 0xffff), q3 = bf2f(qu.y >> 16);
        float p = q0 * ks.x + q1 * ks.y + q2 * ks.z + q3 * ks.w;
        p += __shfl_xor(p, 1);
        p += __shfl_xor(p, 2);
        p += __shfl_xor(p, 4);
        float z = (float)L_SEQ / (p + 1e-6f);
        uint2 o;
        o.x = (u32)f2bf(q0 * z) | ((u32)f2bf(q1 * z) << 16);
        o.y = (u32)f2bf(q2 * z) | ((u32)f2bf(q3 * z) << 16);
        *(uint2*)qp = o;
    }
}

// ---------------------------------------------------------------------------
extern "C" void kernel_launch(void* const* d_in, const int* in_sizes, int n_in,
                              void* d_out, int out_size, void* d_ws, size_t ws_size,
                              hipStream_t stream)
{
    const float* x  = (const float*)d_in[0];
    const float* Wq = (const float*)d_in[1];
    const float* Wk = (const float*)d_in[2];
    const float* Wv = (const float*)d_in[3];
    const float* Wm = (const float*)d_in[4];
    const float* W1 = (const float*)d_in[5];
    const float* W2 = (const float*)d_in[6];
    const float* g1 = (const float*)d_in[7];
    const float* b1 = (const float*)d_in[8];
    const float* g2 = (const float*)d_in[9];
    const float* b2 = (const float*)d_in[10];
    float* out = (float*)d_out;

    u16* xb  = (u16*)d_ws;          // slab 0
    u16* q   = xb + SLAB_E;         // slab 1  (q' after attn_z; h-lo after)
    u16* k   = q + SLAB_E;          // slab 2  (dead after kv -> h-hi)
    u16* v   = k + SLAB_E;          // slab 3  (dead after kv)
    u16* ln1 = v + SLAB_E;          // slab 4
    u16* h   = q;                   // spans q..k (M x 512), q'/k dead by then
    // weights (transposed bf16) + small buffers
    u16* wqkvt = ln1 + SLAB_E;             // 768*256
    u16* wmt   = wqkvt + 768 * 256;        // 256*256
    u16* w1t   = wmt + 256 * 256;          // 512*512
    u16* w2t   = w1t + 512 * 512;          // 256*512
    u16* bdr   = w2t + 256 * 512;          // 4*256*256
    u16* bdwt  = bdr + (size_t)N_BATCH * 256 * 256;   // 4*256*256, [c][b*256+k]
    float* Ksum = (float*)(bdwt + (size_t)N_BATCH * 256 * 256);
    float* part = Ksum + (size_t)N_BATCH * N_HEAD * D_H;

    dim3 blk(256);
    const float invL = 1.0f / (float)L_SEQ;

    // ---- prep (convert + all weight transposes, one launch) ----
    prep_all<<<2688, blk, 0, stream>>>(x, xb, (int)(SLAB_E / 8),
                                       Wq, Wk, Wv, Wm, W1, W2,
                                       wqkvt, wmt, w1t, w2t);

    // ---- fused QKV projection -> dense q,k,v slabs (128x128 tiles, nx=6) ----
    gemm128<4><<<(M_ROWS / 128) * 6, blk, 0, stream>>>(
        xb, xb, 256, 256, 256, wqkvt, 256, 0, q, 256, 256, invL, 6);

    // ---- KV reduction (+ fused bdr build) ----
    kv_partial<<<N_BATCH * N_HEAD * KV_SPLIT, blk, 0, stream>>>(k, v, 256, part);
    kv_final<<<N_BATCH * N_HEAD, blk, 0, stream>>>(part, Ksum, bdr);

    // ---- BDW = BD @ Wm (tiny GEMM), bdwt[c][b*256+k] ----
    gemm128<0><<<16, blk, 0, stream>>>(
        wmt, wmt, 256, 256, 256, bdr, 256, 0, bdwt, 1024, 256, 1.f, 8);

    // ---- q' = q * z (in place) ----
    attn_z<<<M_ROWS / NT_TOK, blk, 0, stream>>>(q, Ksum);

    // ---- ln1 = LN(q' @ BDW_b; g1,b1)  (fused epilogue) ----
    gemm_ln<5><<<M_ROWS / 128, blk, 0, stream>>>(
        q, q, 256, 256, 256, bdwt, 1024, 256, ln1, 256, 256, 1.f, 1,
        g1, b1, nullptr, nullptr);

    // ---- h = relu(concat(xb, ln1) @ W1)  (128x128 tiles, nx=4) ----
    gemm128<3><<<(M_ROWS / 128) * 4, blk, 0, stream>>>(
        xb, ln1, 256, 256, 256, w1t, 512, 0, h, 512, 512, 1.f, 4);

    // ---- out = x + LN(h @ W2; g2,b2)  (fused epilogue, f32 out) ----
    gemm_ln<6><<<M_ROWS / 128, blk, 0, stream>>>(
        h, h, 512, 512, 512, w2t, 512, 0, nullptr, 256, 512, 1.f, 1,
        g2, b2, x, out);
}